// Round 16
// baseline (315.510 us; speedup 1.0000x reference)
//
#include <hip/hip_runtime.h>

// R16: revert projqk to BK=64 (R14 form — BK=128's 256B-row swizzle caused
// 6.3M bank conflicts, +13us). Keep out_gemm16 BK=128 (its chain-halving
// gained ~13us despite the layout). Rest = R15/R14.

#define L_SEQ 2048
#define NBATCH 4
#define DMODEL 1024
#define NHEAD 8
#define SCALING 0.08838834764831845f
#define NQ (2048L * 4 * 1024)

typedef _Float16 f16x8 __attribute__((ext_vector_type(8)));
typedef float f32x4 __attribute__((ext_vector_type(4)));

#define GLOBAL_AS __attribute__((address_space(1)))
#define LDS_AS __attribute__((address_space(3)))

__device__ __forceinline__ unsigned short f2h_bits(float x) {
  _Float16 h = (_Float16)x;
  return __builtin_bit_cast(unsigned short, h);
}

__device__ __forceinline__ void gl_lds16(const void* g, void* l) {
  __builtin_amdgcn_global_load_lds((GLOBAL_AS void*)g, (LDS_AS void*)l, 16, 0, 0);
}

// ---------------------------------------------------------------------------
// prep (R14): z<3 weight transposes; z==3 bias_proj + Zsum zero.
// ---------------------------------------------------------------------------
__global__ __launch_bounds__(256) void prep(
    const float* __restrict__ Wq, const float* __restrict__ Wk,
    const float* __restrict__ Wo,
    _Float16* __restrict__ WqT, _Float16* __restrict__ WkT,
    _Float16* __restrict__ WoT,
    const float* __restrict__ bv, float* __restrict__ bvo,
    float4* __restrict__ Zsum4)
{
  const int z = (int)blockIdx.z;
  const int tid = threadIdx.y * 32 + threadIdx.x;
  if (z == 3) {
    if (blockIdx.y == 0 && blockIdx.x < 4) {
      int j = blockIdx.x * 256 + tid;
      float acc = 0.f;
      for (int i = 0; i < DMODEL; ++i) acc += bv[i] * Wo[(long)i * DMODEL + j];
      bvo[j] = acc;
    } else if (blockIdx.y == 1 || blockIdx.y == 2) {
      long idx = ((long)(blockIdx.y - 1) * 32 + blockIdx.x) * 256 + tid;
      if (idx < (long)NBATCH * NHEAD * L_SEQ / 4)
        Zsum4[idx] = (float4){0.f, 0.f, 0.f, 0.f};
    }
    return;
  }
  __shared__ _Float16 tile[32][33];
  const float* in = z == 0 ? Wq : (z == 1 ? Wk : Wo);
  _Float16* outp = z == 0 ? WqT : (z == 1 ? WkT : WoT);
  int r0 = blockIdx.y * 32, c0 = blockIdx.x * 32;
  for (int i = threadIdx.y; i < 32; i += 8)
    tile[i][threadIdx.x] = (_Float16)in[(long)(r0 + i) * 1024 + c0 + threadIdx.x];
  __syncthreads();
  for (int i = threadIdx.y; i < 32; i += 8)
    outp[(long)(c0 + i) * 1024 + r0 + threadIdx.x] = tile[threadIdx.x][i];
}

// ---------------------------------------------------------------------------
__global__ __launch_bounds__(256) void cvt3(
    const float* __restrict__ q, const float* __restrict__ k,
    const float* __restrict__ v, _Float16* __restrict__ xh)
{
  long i = ((long)blockIdx.x * 256 + threadIdx.x) * 8;
  if (i >= 3 * NQ) return;
  int which = (int)(i / NQ);
  const float* src = which == 0 ? q : (which == 1 ? k : v);
  long off = i - (long)which * NQ;
  float4 a = *(const float4*)(src + off);
  float4 b = *(const float4*)(src + off + 4);
  f16x8 h;
  h[0] = (_Float16)a.x; h[1] = (_Float16)a.y; h[2] = (_Float16)a.z; h[3] = (_Float16)a.w;
  h[4] = (_Float16)b.x; h[5] = (_Float16)b.y; h[6] = (_Float16)b.z; h[7] = (_Float16)b.w;
  *(f16x8*)(xh + i) = h;
}

// ---------------------------------------------------------------------------
// gemm16: 128x128 tile. Retained for the small Wvo prep GEMM only.
// ---------------------------------------------------------------------------
template <bool AF16, bool BF16>
__global__ __launch_bounds__(256) void gemm16(
    const void* __restrict__ Ap, long lda, long a_bs,
    const void* __restrict__ Bp, long ldb, long b_bs,
    float* __restrict__ C, long ldc, long c_bs,
    _Float16* __restrict__ Ch, long ldch, long ch_bs,
    const float* __restrict__ bias, int bias_row, float alpha, int K,
    int causal, int cmode)
{
  __shared__ __align__(16) _Float16 As[128][64];
  __shared__ __align__(16) _Float16 Bs[128][64];
  const int tid = threadIdx.x;
  const int lane = tid & 63, wv = tid >> 6;
  const int g = lane >> 4, cc = lane & 15;
  const int wm = wv >> 1, wn = wv & 1;
  const long m0 = (long)blockIdx.y * 128;
  const long n0 = (long)blockIdx.x * 128;

  const float* Af = nullptr; const _Float16* Ah = nullptr;
  const float* Bf = nullptr; const _Float16* Bh = nullptr;
  if constexpr (AF16) Ah = (const _Float16*)Ap + (long)blockIdx.z * a_bs;
  else                Af = (const float*)Ap + (long)blockIdx.z * a_bs;
  if constexpr (BF16) Bh = (const _Float16*)Bp + (long)blockIdx.z * b_bs;
  else                Bf = (const float*)Bp + (long)blockIdx.z * b_bs;

  int Keff = K;
  if (causal) { int lim = (int)m0 + 128; if (lim < K) Keff = lim; }
  const int NT = Keff >> 6;

  f32x4 acc[4][4] = {};
  char* AsB = (char*)&As[0][0];
  char* BsB = (char*)&Bs[0][0];

  for (int kt = 0; kt < NT; ++kt) {
    const long k0 = (long)kt << 6;
    __syncthreads();
    if constexpr (AF16) {
#pragma unroll
      for (int i = 0; i < 4; ++i) {
        int r = 32 * wv + 8 * i + (lane >> 3);
        int gc = (lane & 7) ^ (r & 7);
        gl_lds16(Ah + (m0 + r) * lda + k0 + gc * 8, &As[32 * wv + 8 * i][0]);
      }
    } else {
#pragma unroll
      for (int p = 0; p < 8; ++p) {
        int r = p * 16 + (tid >> 4);
        float4 vv = *(const float4*)(Af + (m0 + r) * lda + k0 + (tid & 15) * 4);
        ushort4 hh;
        hh.x = f2h_bits(vv.x); hh.y = f2h_bits(vv.y);
        hh.z = f2h_bits(vv.z); hh.w = f2h_bits(vv.w);
        *(ushort4*)(AsB + r * 128 + (((tid & 15) * 8) ^ ((r & 7) << 4))) = hh;
      }
    }
    if constexpr (BF16) {
#pragma unroll
      for (int i = 0; i < 4; ++i) {
        int r = 32 * wv + 8 * i + (lane >> 3);
        int gc = (lane & 7) ^ (r & 7);
        gl_lds16(Bh + (n0 + r) * ldb + k0 + gc * 8, &Bs[32 * wv + 8 * i][0]);
      }
    } else {
#pragma unroll
      for (int p = 0; p < 8; ++p) {
        int r = p * 16 + (tid >> 4);
        float4 vv = *(const float4*)(Bf + (n0 + r) * ldb + k0 + (tid & 15) * 4);
        ushort4 hh;
        hh.x = f2h_bits(vv.x); hh.y = f2h_bits(vv.y);
        hh.z = f2h_bits(vv.z); hh.w = f2h_bits(vv.w);
        *(ushort4*)(BsB + r * 128 + (((tid & 15) * 8) ^ ((r & 7) << 4))) = hh;
      }
    }
    __syncthreads();
#pragma unroll
    for (int s = 0; s < 2; ++s) {
      f16x8 af[4], bfr[4];
#pragma unroll
      for (int mi = 0; mi < 4; ++mi) {
        int r = wm * 64 + mi * 16 + cc;
        af[mi] = *(const f16x8*)(AsB + r * 128 + ((s * 64 + 16 * g) ^ ((r & 7) << 4)));
      }
#pragma unroll
      for (int ni = 0; ni < 4; ++ni) {
        int r = wn * 64 + ni * 16 + cc;
        bfr[ni] = *(const f16x8*)(BsB + r * 128 + ((s * 64 + 16 * g) ^ ((r & 7) << 4)));
      }
#pragma unroll
      for (int mi = 0; mi < 4; ++mi)
#pragma unroll
        for (int ni = 0; ni < 4; ++ni)
          acc[mi][ni] = __builtin_amdgcn_mfma_f32_16x16x32_f16(af[mi], bfr[ni], acc[mi][ni], 0, 0, 0);
    }
  }

  float* Cp = C ? C + (long)blockIdx.z * c_bs : nullptr;
  _Float16* Chp = Ch ? Ch + (long)blockIdx.z * ch_bs : nullptr;
#pragma unroll
  for (int ni = 0; ni < 4; ++ni) {
    long col = n0 + wn * 64 + ni * 16 + cc;
    float bcol = (bias && !bias_row) ? bias[col] : 0.0f;
#pragma unroll
    for (int mi = 0; mi < 4; ++mi) {
      long row0 = m0 + wm * 64 + mi * 16 + 4 * g;
#pragma unroll
      for (int rg = 0; rg < 4; ++rg) {
        long row = row0 + rg;
        float b = (bias && bias_row) ? bias[row] : bcol;
        float vv = (acc[mi][ni][rg] + b) * alpha;
        if (Cp) Cp[row * ldc + col] = vv;
        if (Chp) {
          if (cmode == 1) {
            long idx = (((row & 3) * NHEAD + (col >> 7)) * (long)L_SEQ + (row >> 2)) * 128 +
                       (col & 127);
            Chp[idx] = (_Float16)vv;
          } else {
            Chp[row * ldch + col] = (_Float16)vv;
          }
        }
      }
    }
  }
}

// ---------------------------------------------------------------------------
// projqk (R14, BK=64, proven 0-conflict): q/k projections in one launch.
// ---------------------------------------------------------------------------
__global__ __launch_bounds__(256) void projqk(
    const _Float16* __restrict__ xh, const _Float16* __restrict__ WqT,
    const _Float16* __restrict__ WkT, const float* __restrict__ bq,
    const float* __restrict__ bk, _Float16* __restrict__ qph,
    _Float16* __restrict__ kph)
{
  __shared__ __align__(16) _Float16 As[64][64];
  __shared__ __align__(16) _Float16 Bs[128][64];
  const int tid = threadIdx.x, lane = tid & 63, wv = tid >> 6;
  const int g = lane >> 4, cc = lane & 15;
  const int wm = wv >> 1, wn = wv & 1;
  const int sel = (int)blockIdx.y;
  const _Float16* A = xh + (long)sel * NQ;
  const _Float16* B = sel ? WkT : WqT;
  const float* bias = sel ? bk : bq;
  const float alpha = sel ? 1.0f : SCALING;
  _Float16* dst = sel ? kph : qph;
  const int fi = (int)blockIdx.x;
  const long m0 = (long)(fi >> 3) * 64;
  const long n0 = (long)(fi & 7) * 128;

  f32x4 acc[2][4] = {};
  char* AsB = (char*)&As[0][0];
  char* BsB = (char*)&Bs[0][0];

  for (int kt = 0; kt < 16; ++kt) {
    const long k0 = (long)kt << 6;
    __syncthreads();
#pragma unroll
    for (int i = 0; i < 2; ++i) {
      int r = 16 * wv + 8 * i + (lane >> 3);
      int gc = (lane & 7) ^ (r & 7);
      gl_lds16(A + (m0 + r) * 1024 + k0 + gc * 8, &As[16 * wv + 8 * i][0]);
    }
#pragma unroll
    for (int i = 0; i < 4; ++i) {
      int r = 32 * wv + 8 * i + (lane >> 3);
      int gc = (lane & 7) ^ (r & 7);
      gl_lds16(B + (n0 + r) * 1024 + k0 + gc * 8, &Bs[32 * wv + 8 * i][0]);
    }
    __syncthreads();
#pragma unroll
    for (int s = 0; s < 2; ++s) {
      f16x8 af[2], bfr[4];
#pragma unroll
      for (int mi = 0; mi < 2; ++mi) {
        int r = wm * 32 + mi * 16 + cc;
        af[mi] = *(const f16x8*)(AsB + r * 128 + ((s * 64 + 16 * g) ^ ((r & 7) << 4)));
      }
#pragma unroll
      for (int ni = 0; ni < 4; ++ni) {
        int r = wn * 64 + ni * 16 + cc;
        bfr[ni] = *(const f16x8*)(BsB + r * 128 + ((s * 64 + 16 * g) ^ ((r & 7) << 4)));
      }
#pragma unroll
      for (int mi = 0; mi < 2; ++mi)
#pragma unroll
        for (int ni = 0; ni < 4; ++ni)
          acc[mi][ni] = __builtin_amdgcn_mfma_f32_16x16x32_f16(af[mi], bfr[ni], acc[mi][ni], 0, 0, 0);
    }
  }

#pragma unroll
  for (int ni = 0; ni < 4; ++ni) {
    long col = n0 + wn * 64 + ni * 16 + cc;
    float bcol = bias[col];
#pragma unroll
    for (int mi = 0; mi < 2; ++mi) {
      long row0 = m0 + wm * 32 + mi * 16 + 4 * g;
#pragma unroll
      for (int rg = 0; rg < 4; ++rg) {
        long row = row0 + rg;
        float vv = (acc[mi][ni][rg] + bcol) * alpha;
        long idx = (((row & 3) * NHEAD + (col >> 7)) * (long)L_SEQ + (row >> 2)) * 128 +
                   (col & 127);
        dst[idx] = (_Float16)vv;
      }
    }
  }
}

// ---------------------------------------------------------------------------
// proj64 (R8, proven): 64x128 tile, BK=64 dual gl_lds staging. For voT.
// ---------------------------------------------------------------------------
__global__ __launch_bounds__(256) void proj64(
    const _Float16* __restrict__ Ap, long lda, long a_bs,
    const _Float16* __restrict__ Bp, long ldb, long b_bs,
    _Float16* __restrict__ Ch, long ldch, long ch_bs,
    const float* __restrict__ bias, int bias_row, float alpha, int K,
    int cmode, int ntiles)
{
  __shared__ __align__(16) _Float16 As[64][64];
  __shared__ __align__(16) _Float16 Bs[128][64];
  const int tid = threadIdx.x, lane = tid & 63, wv = tid >> 6;
  const int g = lane >> 4, cc = lane & 15;
  const int wm = wv >> 1, wn = wv & 1;
  const int fi = (int)blockIdx.x;
  const int by = fi / ntiles, nc = fi % ntiles;
  const long m0 = (long)by * 64;
  const long n0 = (long)nc * 128;
  const _Float16* A = Ap + (long)blockIdx.z * a_bs;
  const _Float16* B = Bp + (long)blockIdx.z * b_bs;
  const int NT = K >> 6;

  f32x4 acc[2][4] = {};
  char* AsB = (char*)&As[0][0];
  char* BsB = (char*)&Bs[0][0];

  for (int kt = 0; kt < NT; ++kt) {
    const long k0 = (long)kt << 6;
    __syncthreads();
#pragma unroll
    for (int i = 0; i < 2; ++i) {
      int r = 16 * wv + 8 * i + (lane >> 3);
      int gc = (lane & 7) ^ (r & 7);
      gl_lds16(A + (m0 + r) * lda + k0 + gc * 8, &As[16 * wv + 8 * i][0]);
    }
#pragma unroll
    for (int i = 0; i < 4; ++i) {
      int r = 32 * wv + 8 * i + (lane >> 3);
      int gc = (lane & 7) ^ (r & 7);
      gl_lds16(B + (n0 + r) * ldb + k0 + gc * 8, &Bs[32 * wv + 8 * i][0]);
    }
    __syncthreads();
#pragma unroll
    for (int s = 0; s < 2; ++s) {
      f16x8 af[2], bfr[4];
#pragma unroll
      for (int mi = 0; mi < 2; ++mi) {
        int r = wm * 32 + mi * 16 + cc;
        af[mi] = *(const f16x8*)(AsB + r * 128 + ((s * 64 + 16 * g) ^ ((r & 7) << 4)));
      }
#pragma unroll
      for (int ni = 0; ni < 4; ++ni) {
        int r = wn * 64 + ni * 16 + cc;
        bfr[ni] = *(const f16x8*)(BsB + r * 128 + ((s * 64 + 16 * g) ^ ((r & 7) << 4)));
      }
#pragma unroll
      for (int mi = 0; mi < 2; ++mi)
#pragma unroll
        for (int ni = 0; ni < 4; ++ni)
          acc[mi][ni] = __builtin_amdgcn_mfma_f32_16x16x32_f16(af[mi], bfr[ni], acc[mi][ni], 0, 0, 0);
    }
  }

  _Float16* Chp = Ch + (long)blockIdx.z * ch_bs;
#pragma unroll
  for (int ni = 0; ni < 4; ++ni) {
    long col = n0 + wn * 64 + ni * 16 + cc;
    float bcol = bias_row ? 0.0f : bias[col];
#pragma unroll
    for (int mi = 0; mi < 2; ++mi) {
      long row0 = m0 + wm * 32 + mi * 16 + 4 * g;
#pragma unroll
      for (int rg = 0; rg < 4; ++rg) {
        long row = row0 + rg;
        float b = bias_row ? bias[row] : bcol;
        float vv = (acc[mi][ni][rg] + b) * alpha;
        if (cmode == 1) {
          long idx = (((row & 3) * NHEAD + (col >> 7)) * (long)L_SEQ + (row >> 2)) * 128 +
                     (col & 127);
          Chp[idx] = (_Float16)vv;
        } else {
          Chp[row * ldch + col] = (_Float16)vv;
        }
      }
    }
  }
}

// ---------------------------------------------------------------------------
// out_gemm16 (R15, BK=128 — kept: chain-halving gained ~13us): out = wm16 @
// voT^T + bo, causal, NT=(by+2)>>1, 48KB LDS, 1024 blocks heavy-first.
// ---------------------------------------------------------------------------
__global__ __launch_bounds__(256) void out_gemm16(
    const _Float16* __restrict__ wm16, const _Float16* __restrict__ voT,
    const float* __restrict__ bo, float* __restrict__ out)
{
  __shared__ __align__(16) _Float16 As[64][128];   // 16 KB
  __shared__ __align__(16) _Float16 Bs[128][128];  // 32 KB
  const int tid = threadIdx.x, lane = tid & 63, wv = tid >> 6;
  const int g = lane >> 4, cc = lane & 15;
  const int wm = wv >> 1, wn = wv & 1;
  const int fi = (int)blockIdx.x;
  const int by = 31 - (fi >> 5);
  const int j = fi & 31;
  const int nb = j >> 3, nc = j & 7;
  const long m0 = (long)by * 64;
  const long n0 = (long)nc * 128;
  const _Float16* A = wm16 + (long)nb * L_SEQ * L_SEQ;
  const _Float16* B = voT + (long)nb * 2048L * 1024;
  const int NT = (by + 2) >> 1;
  const int srow = lane >> 4, scl = lane & 15;

  f32x4 acc[2][4] = {};
  char* AsB = (char*)&As[0][0];
  char* BsB = (char*)&Bs[0][0];

  for (int kt = 0; kt < NT; ++kt) {
    const long k0 = (long)kt << 7;
    __syncthreads();
#pragma unroll
    for (int i = 0; i < 4; ++i) {
      int r = 16 * wv + 4 * i + srow;
      int gc = scl ^ (r & 7);
      gl_lds16(A + (m0 + r) * 2048 + k0 + gc * 8, &As[16 * wv + 4 * i][0]);
    }
#pragma unroll
    for (int i = 0; i < 8; ++i) {
      int r = 32 * wv + 4 * i + srow;
      int gc = scl ^ (r & 7);
      gl_lds16(B + (n0 + r) * 2048 + k0 + gc * 8, &Bs[32 * wv + 4 * i][0]);
    }
    __syncthreads();
#pragma unroll
    for (int s = 0; s < 4; ++s) {
      f16x8 af[2], bfr[4];
#pragma unroll
      for (int mi = 0; mi < 2; ++mi) {
        int r = wm * 32 + mi * 16 + cc;
        af[mi] = *(const f16x8*)(AsB + r * 256 + (((4 * s + g) ^ (r & 7)) << 4));
      }
#pragma unroll
      for (int ni = 0; ni < 4; ++ni) {
        int r = wn * 64 + ni * 16 + cc;
        bfr[ni] = *(const f16x8*)(BsB + r * 256 + (((4 * s + g) ^ (r & 7)) << 4));
      }
#pragma unroll
      for (int mi = 0; mi < 2; ++mi)
#pragma unroll
        for (int ni = 0; ni < 4; ++ni)
          acc[mi][ni] = __builtin_amdgcn_mfma_f32_16x16x32_f16(af[mi], bfr[ni], acc[mi][ni], 0, 0, 0);
    }
  }

#pragma unroll
  for (int ni = 0; ni < 4; ++ni) {
    long col = n0 + wn * 64 + ni * 16 + cc;
    float b = bo[col];
#pragma unroll
    for (int mi = 0; mi < 2; ++mi) {
      long l0 = m0 + wm * 32 + mi * 16 + 4 * g;
#pragma unroll
      for (int rg = 0; rg < 4; ++rg)
        out[(l0 + rg) * 4096 + nb * 1024 + col] = acc[mi][ni][rg] + b;
    }
  }
}

// ---------------------------------------------------------------------------
// S1 (R10, proven): K-split partial Zsum via atomicAdd. 80-segment grid.
// ---------------------------------------------------------------------------
__global__ __launch_bounds__(256) void s1_kernel(
    const _Float16* __restrict__ qph, const _Float16* __restrict__ kph,
    float* __restrict__ Zsum)
{
  __shared__ __align__(16) _Float16 Qs[64][128];
  __shared__ __align__(16) _Float16 Ks[64][128];
  const int tid = threadIdx.x, lane = tid & 63, w = tid >> 6;
  const int g = lane >> 4, cc = lane & 15;
  const int h = blockIdx.y, nb = blockIdx.z;
  int fi = 79 - (int)blockIdx.x;
  int by, seg;
  if (fi < 8)       { by = fi;                  seg = 0; }
  else if (fi < 24) { int t = fi - 8;  by = 8  + (t >> 1); seg = t & 1; }
  else if (fi < 48) { int t = fi - 24; by = 16 + t / 3;    seg = t % 3; }
  else              { int t = fi - 48; by = 24 + (t >> 2); seg = t & 3; }
  const int lb = by * 64;
  const int c0 = seg * 8;
  const int cEnd = min(c0 + 8, by + 1);
  const int srow = lane >> 4, scl = lane & 15;
  const long hb = ((long)(nb * NHEAD + h)) * L_SEQ * 128;
  char* QsB = (char*)&Qs[0][0];
  char* KsB = (char*)&Ks[0][0];

#pragma unroll
  for (int i = 0; i < 4; ++i) {
    int r = 16 * w + 4 * i + srow;
    int gc = scl ^ (r & 7);
    gl_lds16(&qph[hb + (long)(lb + r) * 128 + gc * 8], &Qs[16 * w + 4 * i][0]);
  }
  auto stageK = [&](int ch) {
#pragma unroll
    for (int i = 0; i < 4; ++i) {
      int r = 16 * w + 4 * i + srow;
      int gc = scl ^ (r & 7);
      gl_lds16(&kph[hb + (long)(ch * 64 + r) * 128 + gc * 8], &Ks[16 * w + 4 * i][0]);
    }
  };
  stageK(c0);
  __syncthreads();

  f16x8 qf[4];
  {
    int r = 16 * w + cc;
#pragma unroll
    for (int s = 0; s < 4; ++s)
      qf[s] = *(const f16x8*)(QsB + r * 256 + ((64 * s + 16 * g) ^ ((r & 7) << 4)));
  }

  f32x4 zacc = {0.f, 0.f, 0.f, 0.f};
  const int l0 = lb + 16 * w + 4 * g;
  for (int ch = c0; ch < cEnd; ++ch) {
#pragma unroll
    for (int t = 0; t < 4; ++t) {
      int kr = 16 * t + cc;
      f32x4 acc = {0.f, 0.f, 0.f, 0.f};
#pragma unroll
      for (int s = 0; s < 4; ++s) {
        f16x8 kf = *(const f16x8*)(KsB + kr * 256 + ((64 * s + 16 * g) ^ ((kr & 7) << 4)));
        acc = __builtin_amdgcn_mfma_f32_16x16x32_f16(qf[s], kf, acc, 0, 0, 0);
      }
      int m = ch * 64 + 16 * t + cc;
#pragma unroll
      for (int rg = 0; rg < 4; ++rg) {
        float e = __expf(acc[rg]);
        zacc[rg] += (m <= l0 + rg) ? e : 0.f;
      }
    }
    if (ch + 1 < cEnd) {
      __syncthreads();
      stageK(ch + 1);
      __syncthreads();
    }
  }
#pragma unroll
  for (int rg = 0; rg < 4; ++rg) {
    float vv = zacc[rg];
    vv += __shfl_xor(vv, 1, 16);
    vv += __shfl_xor(vv, 2, 16);
    vv += __shfl_xor(vv, 4, 16);
    vv += __shfl_xor(vv, 8, 16);
    if (cc == 0)
      atomicAdd(&Zsum[((long)nb * NHEAD + h) * L_SEQ + l0 + rg], vv);
  }
}

// ---------------------------------------------------------------------------
__global__ __launch_bounds__(256) void zero_fill(float* __restrict__ wmean)
{
  int t = (int)blockIdx.x, nb = (int)blockIdx.y;
  int by = 0, rem = t;
  while (rem >= 15 - by) { rem -= 15 - by; ++by; }
  const int mc = by + 1 + rem;
  const int tr = threadIdx.x >> 1, th = threadIdx.x & 1;
  float4 z4 = {0.f, 0.f, 0.f, 0.f};
  float* p = wmean + (long)nb * L_SEQ * L_SEQ + (long)(by * 128 + tr) * L_SEQ +
             mc * 128 + th * 64;
#pragma unroll
  for (int j = 0; j < 16; ++j) ((float4*)p)[j] = z4;
}

// ---------------------------------------------------------------------------
// S2 (R14, proven): 64l x 128m tiles, 272/batch heavy-first + XCD swizzle.
// ---------------------------------------------------------------------------
__global__ __launch_bounds__(256) void s2_kernel(
    const _Float16* __restrict__ qph, const _Float16* __restrict__ kph,
    const float* __restrict__ Zsum, float* __restrict__ wmean,
    _Float16* __restrict__ wm16)
{
  __shared__ __align__(16) _Float16 Qs[64][128];
  __shared__ __align__(16) _Float16 Ks[128][128];
  __shared__ float zl[NHEAD][64];
  const int tid = threadIdx.x, lane = tid & 63, w = tid >> 6;
  const int g = lane >> 4, cc = lane & 15;
  const int nb = blockIdx.y;
  int b = (int)blockIdx.x;
  int bx = (b & 7) * 34 + (b >> 3);          // XCD swizzle (272 = 8*34)
  int rem = 271 - bx;                        // heavy (large-by) first
  int by = 0;
  while (rem >= (by >> 1) + 1) { rem -= (by >> 1) + 1; ++by; }
  const int mc = rem;
  const int lb = by * 64, mb = mc * 128;
  const bool diag = (mb + 127 > lb);
  const int srow = lane >> 4, scl = lane & 15;
  char* QsB = (char*)&Qs[0][0];
  char* KsB = (char*)&Ks[0][0];

  for (int i = tid; i < NHEAD * 64; i += 256)
    zl[i >> 6][i & 63] =
        1.0f / (8.0f * Zsum[((long)nb * NHEAD + (i >> 6)) * L_SEQ + lb + (i & 63)]);

  auto stage = [&](int h) {
    const long qb = ((long)(nb * NHEAD + h) * L_SEQ + lb) * 128;
    const long kb = ((long)(nb * NHEAD + h) * L_SEQ + mb) * 128;
#pragma unroll
    for (int i = 0; i < 4; ++i) {
      int r = 16 * w + 4 * i + srow;
      int gc = scl ^ (r & 7);
      gl_lds16(&qph[qb + (long)r * 128 + gc * 8], &Qs[16 * w + 4 * i][0]);
    }
#pragma unroll
    for (int i = 0; i < 8; ++i) {
      int r = 32 * w + 4 * i + srow;
      int gc = scl ^ (r & 7);
      gl_lds16(&kph[kb + (long)r * 128 + gc * 8], &Ks[32 * w + 4 * i][0]);
    }
  };
  stage(0);
  __syncthreads();

  f32x4 wacc[8] = {};
  const int l0 = lb + 16 * w + 4 * g;
  for (int h = 0; h < NHEAD; ++h) {
    f16x8 qf[4];
    int qr = 16 * w + cc;
#pragma unroll
    for (int s = 0; s < 4; ++s)
      qf[s] = *(const f16x8*)(QsB + qr * 256 + ((64 * s + 16 * g) ^ ((qr & 7) << 4)));
    f32x4 zv = *(const f32x4*)&zl[h][16 * w + 4 * g];
#pragma unroll
    for (int t = 0; t < 8; ++t) {
      int kr = 16 * t + cc;
      f32x4 acc = {0.f, 0.f, 0.f, 0.f};
#pragma unroll
      for (int s = 0; s < 4; ++s) {
        f16x8 kf = *(const f16x8*)(KsB + kr * 256 + ((64 * s + 16 * g) ^ ((kr & 7) << 4)));
        acc = __builtin_amdgcn_mfma_f32_16x16x32_f16(qf[s], kf, acc, 0, 0, 0);
      }
      int m = mb + 16 * t + cc;
#pragma unroll
      for (int rg = 0; rg < 4; ++rg) {
        float e = __expf(acc[rg]) * zv[rg];
        wacc[t][rg] += (!diag || m <= l0 + rg) ? e : 0.f;
      }
    }
    if (h + 1 < NHEAD) {
      __syncthreads();
      stage(h + 1);
      __syncthreads();
    }
  }
  float* wout = wmean + (long)nb * L_SEQ * L_SEQ;
  _Float16* w16 = wm16 + (long)nb * L_SEQ * L_SEQ;
#pragma unroll
  for (int t = 0; t < 8; ++t) {
    int m = mb + 16 * t + cc;
#pragma unroll
    for (int rg = 0; rg < 4; ++rg) {
      long idx = (long)(l0 + rg) * L_SEQ + m;
      wout[idx] = wacc[t][rg];
      w16[idx] = (_Float16)wacc[t][rg];
    }
  }
}

// ---------------------------------------------------------------------------
extern "C" void kernel_launch(void* const* d_in, const int* in_sizes, int n_in,
                              void* d_out, int out_size, void* d_ws, size_t ws_size,
                              hipStream_t stream)
{
  const float* q  = (const float*)d_in[0];
  const float* k  = (const float*)d_in[1];
  const float* v  = (const float*)d_in[2];
  const float* Wq = (const float*)d_in[3];
  const float* bq = (const float*)d_in[4];
  const float* Wk = (const float*)d_in[5];
  const float* bk = (const float*)d_in[6];
  const float* Wv = (const float*)d_in[7];
  const float* bv = (const float*)d_in[8];
  const float* Wo = (const float*)d_in[9];
  const float* bo = (const float*)d_in[10];

  float* out = (float*)d_out;
  float* wmean = out + (long)L_SEQ * NBATCH * DMODEL;

  if (ws_size < (140UL << 20)) return;

  char* ws = (char*)d_ws;
  _Float16* xh   = (_Float16*)(ws);                   // 48 MB (q,k,v f16)
  _Float16* qph  = (_Float16*)(ws + (48L << 20));     // 16 MB head-major
  _Float16* kph  = (_Float16*)(ws + (64L << 20));     // 16 MB head-major
  _Float16* voT  = (_Float16*)(ws + (80L << 20));     // 16 MB
  _Float16* wm16 = (_Float16*)(ws + (96L << 20));     // 33.6 MB (f16 wmean)
  _Float16* WqT  = (_Float16*)(ws + (130L << 20));    // 2 MB
  _Float16* WkT  = (_Float16*)(ws + (132L << 20));    // 2 MB
  _Float16* WoT  = (_Float16*)(ws + (134L << 20));    // 2 MB
  _Float16* WvoT = (_Float16*)(ws + (136L << 20));    // 2 MB
  float*    bvo  = (float*)   (ws + (138L << 20));    // 4 KB
  float*    Zsum = (float*)   (ws + (138L << 20) + (1L << 16));  // 256 KB

  prep<<<dim3(32, 32, 4), dim3(32, 8, 1), 0, stream>>>(
      Wq, Wk, Wo, WqT, WkT, WoT, bv, bvo, (float4*)Zsum);
  gemm16<true, false><<<dim3(8, 8, 1), 256, 0, stream>>>(
      WoT, 1024, 0, Wv, 1024, 0,
      (float*)nullptr, 0, 0, WvoT, 1024, 0,
      (const float*)nullptr, 0, 1.0f, 1024, 0, 0);
  cvt3<<<dim3(12288, 1, 1), 256, 0, stream>>>(q, k, v, xh);
  projqk<<<dim3(1024, 2, 1), 256, 0, stream>>>(xh, WqT, WkT, bq, bk, qph, kph);
  proj64<<<dim3(256, 1, 4), 256, 0, stream>>>(
      WvoT, 1024, 0, xh + 2 * NQ, 4096, 1024, voT, 2048, 2048L * 1024,
      bvo, 1, 1.0f, 1024, 0, 16);
  s1_kernel<<<dim3(80, NHEAD, NBATCH), 256, 0, stream>>>(qph, kph, Zsum);
  zero_fill<<<dim3(120, 4, 1), 256, 0, stream>>>(wmean);
  s2_kernel<<<dim3(272, NBATCH, 1), 256, 0, stream>>>(qph, kph, Zsum, wmean, wm16);
  out_gemm16<<<dim3(1024, 1, 1), 256, 0, stream>>>(wm16, voT, bo, out);
}

// Round 17
// 308.630 us; speedup vs baseline: 1.0223x; 1.0223x over previous
//
#include <hip/hip_runtime.h>

// R17: XCD-affinity remaps. projqk: A-tile-sharing blocks colocated per XCD
// (was: 8 XCDs each filling the same A-tile -> FETCH 134MB vs 36MB ideal).
// out_gemm16: same for (by,nb) A-panels, heavy-by still first. Index-math
// only; rest = R16.

#define L_SEQ 2048
#define NBATCH 4
#define DMODEL 1024
#define NHEAD 8
#define SCALING 0.08838834764831845f
#define NQ (2048L * 4 * 1024)

typedef _Float16 f16x8 __attribute__((ext_vector_type(8)));
typedef float f32x4 __attribute__((ext_vector_type(4)));

#define GLOBAL_AS __attribute__((address_space(1)))
#define LDS_AS __attribute__((address_space(3)))

__device__ __forceinline__ unsigned short f2h_bits(float x) {
  _Float16 h = (_Float16)x;
  return __builtin_bit_cast(unsigned short, h);
}

__device__ __forceinline__ void gl_lds16(const void* g, void* l) {
  __builtin_amdgcn_global_load_lds((GLOBAL_AS void*)g, (LDS_AS void*)l, 16, 0, 0);
}

// ---------------------------------------------------------------------------
// prep (R14): z<3 weight transposes; z==3 bias_proj + Zsum zero.
// ---------------------------------------------------------------------------
__global__ __launch_bounds__(256) void prep(
    const float* __restrict__ Wq, const float* __restrict__ Wk,
    const float* __restrict__ Wo,
    _Float16* __restrict__ WqT, _Float16* __restrict__ WkT,
    _Float16* __restrict__ WoT,
    const float* __restrict__ bv, float* __restrict__ bvo,
    float4* __restrict__ Zsum4)
{
  const int z = (int)blockIdx.z;
  const int tid = threadIdx.y * 32 + threadIdx.x;
  if (z == 3) {
    if (blockIdx.y == 0 && blockIdx.x < 4) {
      int j = blockIdx.x * 256 + tid;
      float acc = 0.f;
      for (int i = 0; i < DMODEL; ++i) acc += bv[i] * Wo[(long)i * DMODEL + j];
      bvo[j] = acc;
    } else if (blockIdx.y == 1 || blockIdx.y == 2) {
      long idx = ((long)(blockIdx.y - 1) * 32 + blockIdx.x) * 256 + tid;
      if (idx < (long)NBATCH * NHEAD * L_SEQ / 4)
        Zsum4[idx] = (float4){0.f, 0.f, 0.f, 0.f};
    }
    return;
  }
  __shared__ _Float16 tile[32][33];
  const float* in = z == 0 ? Wq : (z == 1 ? Wk : Wo);
  _Float16* outp = z == 0 ? WqT : (z == 1 ? WkT : WoT);
  int r0 = blockIdx.y * 32, c0 = blockIdx.x * 32;
  for (int i = threadIdx.y; i < 32; i += 8)
    tile[i][threadIdx.x] = (_Float16)in[(long)(r0 + i) * 1024 + c0 + threadIdx.x];
  __syncthreads();
  for (int i = threadIdx.y; i < 32; i += 8)
    outp[(long)(c0 + i) * 1024 + r0 + threadIdx.x] = tile[threadIdx.x][i];
}

// ---------------------------------------------------------------------------
__global__ __launch_bounds__(256) void cvt3(
    const float* __restrict__ q, const float* __restrict__ k,
    const float* __restrict__ v, _Float16* __restrict__ xh)
{
  long i = ((long)blockIdx.x * 256 + threadIdx.x) * 8;
  if (i >= 3 * NQ) return;
  int which = (int)(i / NQ);
  const float* src = which == 0 ? q : (which == 1 ? k : v);
  long off = i - (long)which * NQ;
  float4 a = *(const float4*)(src + off);
  float4 b = *(const float4*)(src + off + 4);
  f16x8 h;
  h[0] = (_Float16)a.x; h[1] = (_Float16)a.y; h[2] = (_Float16)a.z; h[3] = (_Float16)a.w;
  h[4] = (_Float16)b.x; h[5] = (_Float16)b.y; h[6] = (_Float16)b.z; h[7] = (_Float16)b.w;
  *(f16x8*)(xh + i) = h;
}

// ---------------------------------------------------------------------------
// gemm16: 128x128 tile. Retained for the small Wvo prep GEMM only.
// ---------------------------------------------------------------------------
template <bool AF16, bool BF16>
__global__ __launch_bounds__(256) void gemm16(
    const void* __restrict__ Ap, long lda, long a_bs,
    const void* __restrict__ Bp, long ldb, long b_bs,
    float* __restrict__ C, long ldc, long c_bs,
    _Float16* __restrict__ Ch, long ldch, long ch_bs,
    const float* __restrict__ bias, int bias_row, float alpha, int K,
    int causal, int cmode)
{
  __shared__ __align__(16) _Float16 As[128][64];
  __shared__ __align__(16) _Float16 Bs[128][64];
  const int tid = threadIdx.x;
  const int lane = tid & 63, wv = tid >> 6;
  const int g = lane >> 4, cc = lane & 15;
  const int wm = wv >> 1, wn = wv & 1;
  const long m0 = (long)blockIdx.y * 128;
  const long n0 = (long)blockIdx.x * 128;

  const float* Af = nullptr; const _Float16* Ah = nullptr;
  const float* Bf = nullptr; const _Float16* Bh = nullptr;
  if constexpr (AF16) Ah = (const _Float16*)Ap + (long)blockIdx.z * a_bs;
  else                Af = (const float*)Ap + (long)blockIdx.z * a_bs;
  if constexpr (BF16) Bh = (const _Float16*)Bp + (long)blockIdx.z * b_bs;
  else                Bf = (const float*)Bp + (long)blockIdx.z * b_bs;

  int Keff = K;
  if (causal) { int lim = (int)m0 + 128; if (lim < K) Keff = lim; }
  const int NT = Keff >> 6;

  f32x4 acc[4][4] = {};
  char* AsB = (char*)&As[0][0];
  char* BsB = (char*)&Bs[0][0];

  for (int kt = 0; kt < NT; ++kt) {
    const long k0 = (long)kt << 6;
    __syncthreads();
    if constexpr (AF16) {
#pragma unroll
      for (int i = 0; i < 4; ++i) {
        int r = 32 * wv + 8 * i + (lane >> 3);
        int gc = (lane & 7) ^ (r & 7);
        gl_lds16(Ah + (m0 + r) * lda + k0 + gc * 8, &As[32 * wv + 8 * i][0]);
      }
    } else {
#pragma unroll
      for (int p = 0; p < 8; ++p) {
        int r = p * 16 + (tid >> 4);
        float4 vv = *(const float4*)(Af + (m0 + r) * lda + k0 + (tid & 15) * 4);
        ushort4 hh;
        hh.x = f2h_bits(vv.x); hh.y = f2h_bits(vv.y);
        hh.z = f2h_bits(vv.z); hh.w = f2h_bits(vv.w);
        *(ushort4*)(AsB + r * 128 + (((tid & 15) * 8) ^ ((r & 7) << 4))) = hh;
      }
    }
    if constexpr (BF16) {
#pragma unroll
      for (int i = 0; i < 4; ++i) {
        int r = 32 * wv + 8 * i + (lane >> 3);
        int gc = (lane & 7) ^ (r & 7);
        gl_lds16(Bh + (n0 + r) * ldb + k0 + gc * 8, &Bs[32 * wv + 8 * i][0]);
      }
    } else {
#pragma unroll
      for (int p = 0; p < 8; ++p) {
        int r = p * 16 + (tid >> 4);
        float4 vv = *(const float4*)(Bf + (n0 + r) * ldb + k0 + (tid & 15) * 4);
        ushort4 hh;
        hh.x = f2h_bits(vv.x); hh.y = f2h_bits(vv.y);
        hh.z = f2h_bits(vv.z); hh.w = f2h_bits(vv.w);
        *(ushort4*)(BsB + r * 128 + (((tid & 15) * 8) ^ ((r & 7) << 4))) = hh;
      }
    }
    __syncthreads();
#pragma unroll
    for (int s = 0; s < 2; ++s) {
      f16x8 af[4], bfr[4];
#pragma unroll
      for (int mi = 0; mi < 4; ++mi) {
        int r = wm * 64 + mi * 16 + cc;
        af[mi] = *(const f16x8*)(AsB + r * 128 + ((s * 64 + 16 * g) ^ ((r & 7) << 4)));
      }
#pragma unroll
      for (int ni = 0; ni < 4; ++ni) {
        int r = wn * 64 + ni * 16 + cc;
        bfr[ni] = *(const f16x8*)(BsB + r * 128 + ((s * 64 + 16 * g) ^ ((r & 7) << 4)));
      }
#pragma unroll
      for (int mi = 0; mi < 4; ++mi)
#pragma unroll
        for (int ni = 0; ni < 4; ++ni)
          acc[mi][ni] = __builtin_amdgcn_mfma_f32_16x16x32_f16(af[mi], bfr[ni], acc[mi][ni], 0, 0, 0);
    }
  }

  float* Cp = C ? C + (long)blockIdx.z * c_bs : nullptr;
  _Float16* Chp = Ch ? Ch + (long)blockIdx.z * ch_bs : nullptr;
#pragma unroll
  for (int ni = 0; ni < 4; ++ni) {
    long col = n0 + wn * 64 + ni * 16 + cc;
    float bcol = (bias && !bias_row) ? bias[col] : 0.0f;
#pragma unroll
    for (int mi = 0; mi < 4; ++mi) {
      long row0 = m0 + wm * 64 + mi * 16 + 4 * g;
#pragma unroll
      for (int rg = 0; rg < 4; ++rg) {
        long row = row0 + rg;
        float b = (bias && bias_row) ? bias[row] : bcol;
        float vv = (acc[mi][ni][rg] + b) * alpha;
        if (Cp) Cp[row * ldc + col] = vv;
        if (Chp) {
          if (cmode == 1) {
            long idx = (((row & 3) * NHEAD + (col >> 7)) * (long)L_SEQ + (row >> 2)) * 128 +
                       (col & 127);
            Chp[idx] = (_Float16)vv;
          } else {
            Chp[row * ldch + col] = (_Float16)vv;
          }
        }
      }
    }
  }
}

// ---------------------------------------------------------------------------
// projqk (R16 BK=64 + XCD-affinity): blocks sharing an A-tile land on ONE
// XCD (mt = (bid&7)*16 + (j&15)); per-XCD B working set 2MB fits L2.
// ---------------------------------------------------------------------------
__global__ __launch_bounds__(256) void projqk(
    const _Float16* __restrict__ xh, const _Float16* __restrict__ WqT,
    const _Float16* __restrict__ WkT, const float* __restrict__ bq,
    const float* __restrict__ bk, _Float16* __restrict__ qph,
    _Float16* __restrict__ kph)
{
  __shared__ __align__(16) _Float16 As[64][64];
  __shared__ __align__(16) _Float16 Bs[128][64];
  const int tid = threadIdx.x, lane = tid & 63, wv = tid >> 6;
  const int g = lane >> 4, cc = lane & 15;
  const int wm = wv >> 1, wn = wv & 1;
  const int sel = (int)blockIdx.y;
  const _Float16* A = xh + (long)sel * NQ;
  const _Float16* B = sel ? WkT : WqT;
  const float* bias = sel ? bk : bq;
  const float alpha = sel ? 1.0f : SCALING;
  _Float16* dst = sel ? kph : qph;
  const int bid = (int)blockIdx.x;
  const int j = bid >> 3;
  const int mt = (bid & 7) * 16 + (j & 15);   // A-tile pinned to XCD bid&7
  const int nt = j >> 4;
  const long m0 = (long)mt * 64;
  const long n0 = (long)nt * 128;

  f32x4 acc[2][4] = {};
  char* AsB = (char*)&As[0][0];
  char* BsB = (char*)&Bs[0][0];

  for (int kt = 0; kt < 16; ++kt) {
    const long k0 = (long)kt << 6;
    __syncthreads();
#pragma unroll
    for (int i = 0; i < 2; ++i) {
      int r = 16 * wv + 8 * i + (lane >> 3);
      int gc = (lane & 7) ^ (r & 7);
      gl_lds16(A + (m0 + r) * 1024 + k0 + gc * 8, &As[16 * wv + 8 * i][0]);
    }
#pragma unroll
    for (int i = 0; i < 4; ++i) {
      int r = 32 * wv + 8 * i + (lane >> 3);
      int gc = (lane & 7) ^ (r & 7);
      gl_lds16(B + (n0 + r) * 1024 + k0 + gc * 8, &Bs[32 * wv + 8 * i][0]);
    }
    __syncthreads();
#pragma unroll
    for (int s = 0; s < 2; ++s) {
      f16x8 af[2], bfr[4];
#pragma unroll
      for (int mi = 0; mi < 2; ++mi) {
        int r = wm * 32 + mi * 16 + cc;
        af[mi] = *(const f16x8*)(AsB + r * 128 + ((s * 64 + 16 * g) ^ ((r & 7) << 4)));
      }
#pragma unroll
      for (int ni = 0; ni < 4; ++ni) {
        int r = wn * 64 + ni * 16 + cc;
        bfr[ni] = *(const f16x8*)(BsB + r * 128 + ((s * 64 + 16 * g) ^ ((r & 7) << 4)));
      }
#pragma unroll
      for (int mi = 0; mi < 2; ++mi)
#pragma unroll
        for (int ni = 0; ni < 4; ++ni)
          acc[mi][ni] = __builtin_amdgcn_mfma_f32_16x16x32_f16(af[mi], bfr[ni], acc[mi][ni], 0, 0, 0);
    }
  }

#pragma unroll
  for (int ni = 0; ni < 4; ++ni) {
    long col = n0 + wn * 64 + ni * 16 + cc;
    float bcol = bias[col];
#pragma unroll
    for (int mi = 0; mi < 2; ++mi) {
      long row0 = m0 + wm * 32 + mi * 16 + 4 * g;
#pragma unroll
      for (int rg = 0; rg < 4; ++rg) {
        long row = row0 + rg;
        float vv = (acc[mi][ni][rg] + bcol) * alpha;
        long idx = (((row & 3) * NHEAD + (col >> 7)) * (long)L_SEQ + (row >> 2)) * 128 +
                   (col & 127);
        dst[idx] = (_Float16)vv;
      }
    }
  }
}

// ---------------------------------------------------------------------------
// proj64 (R8, proven): 64x128 tile, BK=64 dual gl_lds staging. For voT.
// ---------------------------------------------------------------------------
__global__ __launch_bounds__(256) void proj64(
    const _Float16* __restrict__ Ap, long lda, long a_bs,
    const _Float16* __restrict__ Bp, long ldb, long b_bs,
    _Float16* __restrict__ Ch, long ldch, long ch_bs,
    const float* __restrict__ bias, int bias_row, float alpha, int K,
    int cmode, int ntiles)
{
  __shared__ __align__(16) _Float16 As[64][64];
  __shared__ __align__(16) _Float16 Bs[128][64];
  const int tid = threadIdx.x, lane = tid & 63, wv = tid >> 6;
  const int g = lane >> 4, cc = lane & 15;
  const int wm = wv >> 1, wn = wv & 1;
  const int fi = (int)blockIdx.x;
  const int by = fi / ntiles, nc = fi % ntiles;
  const long m0 = (long)by * 64;
  const long n0 = (long)nc * 128;
  const _Float16* A = Ap + (long)blockIdx.z * a_bs;
  const _Float16* B = Bp + (long)blockIdx.z * b_bs;
  const int NT = K >> 6;

  f32x4 acc[2][4] = {};
  char* AsB = (char*)&As[0][0];
  char* BsB = (char*)&Bs[0][0];

  for (int kt = 0; kt < NT; ++kt) {
    const long k0 = (long)kt << 6;
    __syncthreads();
#pragma unroll
    for (int i = 0; i < 2; ++i) {
      int r = 16 * wv + 8 * i + (lane >> 3);
      int gc = (lane & 7) ^ (r & 7);
      gl_lds16(A + (m0 + r) * lda + k0 + gc * 8, &As[16 * wv + 8 * i][0]);
    }
#pragma unroll
    for (int i = 0; i < 4; ++i) {
      int r = 32 * wv + 8 * i + (lane >> 3);
      int gc = (lane & 7) ^ (r & 7);
      gl_lds16(B + (n0 + r) * ldb + k0 + gc * 8, &Bs[32 * wv + 8 * i][0]);
    }
    __syncthreads();
#pragma unroll
    for (int s = 0; s < 2; ++s) {
      f16x8 af[2], bfr[4];
#pragma unroll
      for (int mi = 0; mi < 2; ++mi) {
        int r = wm * 32 + mi * 16 + cc;
        af[mi] = *(const f16x8*)(AsB + r * 128 + ((s * 64 + 16 * g) ^ ((r & 7) << 4)));
      }
#pragma unroll
      for (int ni = 0; ni < 4; ++ni) {
        int r = wn * 64 + ni * 16 + cc;
        bfr[ni] = *(const f16x8*)(BsB + r * 128 + ((s * 64 + 16 * g) ^ ((r & 7) << 4)));
      }
#pragma unroll
      for (int mi = 0; mi < 2; ++mi)
#pragma unroll
        for (int ni = 0; ni < 4; ++ni)
          acc[mi][ni] = __builtin_amdgcn_mfma_f32_16x16x32_f16(af[mi], bfr[ni], acc[mi][ni], 0, 0, 0);
    }
  }

  _Float16* Chp = Ch + (long)blockIdx.z * ch_bs;
#pragma unroll
  for (int ni = 0; ni < 4; ++ni) {
    long col = n0 + wn * 64 + ni * 16 + cc;
    float bcol = bias_row ? 0.0f : bias[col];
#pragma unroll
    for (int mi = 0; mi < 2; ++mi) {
      long row0 = m0 + wm * 32 + mi * 16 + 4 * g;
#pragma unroll
      for (int rg = 0; rg < 4; ++rg) {
        long row = row0 + rg;
        float b = bias_row ? bias[row] : bcol;
        float vv = (acc[mi][ni][rg] + b) * alpha;
        if (cmode == 1) {
          long idx = (((row & 3) * NHEAD + (col >> 7)) * (long)L_SEQ + (row >> 2)) * 128 +
                     (col & 127);
          Chp[idx] = (_Float16)vv;
        } else {
          Chp[row * ldch + col] = (_Float16)vv;
        }
      }
    }
  }
}

// ---------------------------------------------------------------------------
// out_gemm16 (BK=128 + XCD-affinity): each (by,nb) A-panel pinned to one XCD
// (p = (j>>3)*8 + (bid&7)); heavy-by groups still dispatch first.
// ---------------------------------------------------------------------------
__global__ __launch_bounds__(256) void out_gemm16(
    const _Float16* __restrict__ wm16, const _Float16* __restrict__ voT,
    const float* __restrict__ bo, float* __restrict__ out)
{
  __shared__ __align__(16) _Float16 As[64][128];   // 16 KB
  __shared__ __align__(16) _Float16 Bs[128][128];  // 32 KB
  const int tid = threadIdx.x, lane = tid & 63, wv = tid >> 6;
  const int g = lane >> 4, cc = lane & 15;
  const int wm = wv >> 1, wn = wv & 1;
  const int bid = (int)blockIdx.x;
  const int j = bid >> 3;
  const int p = (j >> 3) * 8 + (bid & 7);   // (by,nb) group pinned to XCD
  const int by = 31 - (p >> 2);             // heavy (long-K) groups first
  const int nb = p & 3;
  const int nc = j & 7;
  const long m0 = (long)by * 64;
  const long n0 = (long)nc * 128;
  const _Float16* A = wm16 + (long)nb * L_SEQ * L_SEQ;
  const _Float16* B = voT + (long)nb * 2048L * 1024;
  const int NT = (by + 2) >> 1;
  const int srow = lane >> 4, scl = lane & 15;

  f32x4 acc[2][4] = {};
  char* AsB = (char*)&As[0][0];
  char* BsB = (char*)&Bs[0][0];

  for (int kt = 0; kt < NT; ++kt) {
    const long k0 = (long)kt << 7;
    __syncthreads();
#pragma unroll
    for (int i = 0; i < 4; ++i) {
      int r = 16 * wv + 4 * i + srow;
      int gc = scl ^ (r & 7);
      gl_lds16(A + (m0 + r) * 2048 + k0 + gc * 8, &As[16 * wv + 4 * i][0]);
    }
#pragma unroll
    for (int i = 0; i < 8; ++i) {
      int r = 32 * wv + 4 * i + srow;
      int gc = scl ^ (r & 7);
      gl_lds16(B + (n0 + r) * 2048 + k0 + gc * 8, &Bs[32 * wv + 4 * i][0]);
    }
    __syncthreads();
#pragma unroll
    for (int s = 0; s < 4; ++s) {
      f16x8 af[2], bfr[4];
#pragma unroll
      for (int mi = 0; mi < 2; ++mi) {
        int r = wm * 32 + mi * 16 + cc;
        af[mi] = *(const f16x8*)(AsB + r * 256 + (((4 * s + g) ^ (r & 7)) << 4));
      }
#pragma unroll
      for (int ni = 0; ni < 4; ++ni) {
        int r = wn * 64 + ni * 16 + cc;
        bfr[ni] = *(const f16x8*)(BsB + r * 256 + (((4 * s + g) ^ (r & 7)) << 4));
      }
#pragma unroll
      for (int mi = 0; mi < 2; ++mi)
#pragma unroll
        for (int ni = 0; ni < 4; ++ni)
          acc[mi][ni] = __builtin_amdgcn_mfma_f32_16x16x32_f16(af[mi], bfr[ni], acc[mi][ni], 0, 0, 0);
    }
  }

#pragma unroll
  for (int ni = 0; ni < 4; ++ni) {
    long col = n0 + wn * 64 + ni * 16 + cc;
    float b = bo[col];
#pragma unroll
    for (int mi = 0; mi < 2; ++mi) {
      long l0 = m0 + wm * 32 + mi * 16 + 4 * g;
#pragma unroll
      for (int rg = 0; rg < 4; ++rg)
        out[(l0 + rg) * 4096 + nb * 1024 + col] = acc[mi][ni][rg] + b;
    }
  }
}

// ---------------------------------------------------------------------------
// S1 (R10, proven): K-split partial Zsum via atomicAdd. 80-segment grid.
// ---------------------------------------------------------------------------
__global__ __launch_bounds__(256) void s1_kernel(
    const _Float16* __restrict__ qph, const _Float16* __restrict__ kph,
    float* __restrict__ Zsum)
{
  __shared__ __align__(16) _Float16 Qs[64][128];
  __shared__ __align__(16) _Float16 Ks[64][128];
  const int tid = threadIdx.x, lane = tid & 63, w = tid >> 6;
  const int g = lane >> 4, cc = lane & 15;
  const int h = blockIdx.y, nb = blockIdx.z;
  int fi = 79 - (int)blockIdx.x;
  int by, seg;
  if (fi < 8)       { by = fi;                  seg = 0; }
  else if (fi < 24) { int t = fi - 8;  by = 8  + (t >> 1); seg = t & 1; }
  else if (fi < 48) { int t = fi - 24; by = 16 + t / 3;    seg = t % 3; }
  else              { int t = fi - 48; by = 24 + (t >> 2); seg = t & 3; }
  const int lb = by * 64;
  const int c0 = seg * 8;
  const int cEnd = min(c0 + 8, by + 1);
  const int srow = lane >> 4, scl = lane & 15;
  const long hb = ((long)(nb * NHEAD + h)) * L_SEQ * 128;
  char* QsB = (char*)&Qs[0][0];
  char* KsB = (char*)&Ks[0][0];

#pragma unroll
  for (int i = 0; i < 4; ++i) {
    int r = 16 * w + 4 * i + srow;
    int gc = scl ^ (r & 7);
    gl_lds16(&qph[hb + (long)(lb + r) * 128 + gc * 8], &Qs[16 * w + 4 * i][0]);
  }
  auto stageK = [&](int ch) {
#pragma unroll
    for (int i = 0; i < 4; ++i) {
      int r = 16 * w + 4 * i + srow;
      int gc = scl ^ (r & 7);
      gl_lds16(&kph[hb + (long)(ch * 64 + r) * 128 + gc * 8], &Ks[16 * w + 4 * i][0]);
    }
  };
  stageK(c0);
  __syncthreads();

  f16x8 qf[4];
  {
    int r = 16 * w + cc;
#pragma unroll
    for (int s = 0; s < 4; ++s)
      qf[s] = *(const f16x8*)(QsB + r * 256 + ((64 * s + 16 * g) ^ ((r & 7) << 4)));
  }

  f32x4 zacc = {0.f, 0.f, 0.f, 0.f};
  const int l0 = lb + 16 * w + 4 * g;
  for (int ch = c0; ch < cEnd; ++ch) {
#pragma unroll
    for (int t = 0; t < 4; ++t) {
      int kr = 16 * t + cc;
      f32x4 acc = {0.f, 0.f, 0.f, 0.f};
#pragma unroll
      for (int s = 0; s < 4; ++s) {
        f16x8 kf = *(const f16x8*)(KsB + kr * 256 + ((64 * s + 16 * g) ^ ((kr & 7) << 4)));
        acc = __builtin_amdgcn_mfma_f32_16x16x32_f16(qf[s], kf, acc, 0, 0, 0);
      }
      int m = ch * 64 + 16 * t + cc;
#pragma unroll
      for (int rg = 0; rg < 4; ++rg) {
        float e = __expf(acc[rg]);
        zacc[rg] += (m <= l0 + rg) ? e : 0.f;
      }
    }
    if (ch + 1 < cEnd) {
      __syncthreads();
      stageK(ch + 1);
      __syncthreads();
    }
  }
#pragma unroll
  for (int rg = 0; rg < 4; ++rg) {
    float vv = zacc[rg];
    vv += __shfl_xor(vv, 1, 16);
    vv += __shfl_xor(vv, 2, 16);
    vv += __shfl_xor(vv, 4, 16);
    vv += __shfl_xor(vv, 8, 16);
    if (cc == 0)
      atomicAdd(&Zsum[((long)nb * NHEAD + h) * L_SEQ + l0 + rg], vv);
  }
}

// ---------------------------------------------------------------------------
__global__ __launch_bounds__(256) void zero_fill(float* __restrict__ wmean)
{
  int t = (int)blockIdx.x, nb = (int)blockIdx.y;
  int by = 0, rem = t;
  while (rem >= 15 - by) { rem -= 15 - by; ++by; }
  const int mc = by + 1 + rem;
  const int tr = threadIdx.x >> 1, th = threadIdx.x & 1;
  float4 z4 = {0.f, 0.f, 0.f, 0.f};
  float* p = wmean + (long)nb * L_SEQ * L_SEQ + (long)(by * 128 + tr) * L_SEQ +
             mc * 128 + th * 64;
#pragma unroll
  for (int j = 0; j < 16; ++j) ((float4*)p)[j] = z4;
}

// ---------------------------------------------------------------------------
// S2 (R14, proven): 64l x 128m tiles, 272/batch heavy-first + XCD swizzle.
// ---------------------------------------------------------------------------
__global__ __launch_bounds__(256) void s2_kernel(
    const _Float16* __restrict__ qph, const _Float16* __restrict__ kph,
    const float* __restrict__ Zsum, float* __restrict__ wmean,
    _Float16* __restrict__ wm16)
{
  __shared__ __align__(16) _Float16 Qs[64][128];
  __shared__ __align__(16) _Float16 Ks[128][128];
  __shared__ float zl[NHEAD][64];
  const int tid = threadIdx.x, lane = tid & 63, w = tid >> 6;
  const int g = lane >> 4, cc = lane & 15;
  const int nb = blockIdx.y;
  int b = (int)blockIdx.x;
  int bx = (b & 7) * 34 + (b >> 3);          // XCD swizzle (272 = 8*34)
  int rem = 271 - bx;                        // heavy (large-by) first
  int by = 0;
  while (rem >= (by >> 1) + 1) { rem -= (by >> 1) + 1; ++by; }
  const int mc = rem;
  const int lb = by * 64, mb = mc * 128;
  const bool diag = (mb + 127 > lb);
  const int srow = lane >> 4, scl = lane & 15;
  char* QsB = (char*)&Qs[0][0];
  char* KsB = (char*)&Ks[0][0];

  for (int i = tid; i < NHEAD * 64; i += 256)
    zl[i >> 6][i & 63] =
        1.0f / (8.0f * Zsum[((long)nb * NHEAD + (i >> 6)) * L_SEQ + lb + (i & 63)]);

  auto stage = [&](int h) {
    const long qb = ((long)(nb * NHEAD + h) * L_SEQ + lb) * 128;
    const long kb = ((long)(nb * NHEAD + h) * L_SEQ + mb) * 128;
#pragma unroll
    for (int i = 0; i < 4; ++i) {
      int r = 16 * w + 4 * i + srow;
      int gc = scl ^ (r & 7);
      gl_lds16(&qph[qb + (long)r * 128 + gc * 8], &Qs[16 * w + 4 * i][0]);
    }
#pragma unroll
    for (int i = 0; i < 8; ++i) {
      int r = 32 * w + 4 * i + srow;
      int gc = scl ^ (r & 7);
      gl_lds16(&kph[kb + (long)r * 128 + gc * 8], &Ks[32 * w + 4 * i][0]);
    }
  };
  stage(0);
  __syncthreads();

  f32x4 wacc[8] = {};
  const int l0 = lb + 16 * w + 4 * g;
  for (int h = 0; h < NHEAD; ++h) {
    f16x8 qf[4];
    int qr = 16 * w + cc;
#pragma unroll
    for (int s = 0; s < 4; ++s)
      qf[s] = *(const f16x8*)(QsB + qr * 256 + ((64 * s + 16 * g) ^ ((qr & 7) << 4)));
    f32x4 zv = *(const f32x4*)&zl[h][16 * w + 4 * g];
#pragma unroll
    for (int t = 0; t < 8; ++t) {
      int kr = 16 * t + cc;
      f32x4 acc = {0.f, 0.f, 0.f, 0.f};
#pragma unroll
      for (int s = 0; s < 4; ++s) {
        f16x8 kf = *(const f16x8*)(KsB + kr * 256 + ((64 * s + 16 * g) ^ ((kr & 7) << 4)));
        acc = __builtin_amdgcn_mfma_f32_16x16x32_f16(qf[s], kf, acc, 0, 0, 0);
      }
      int m = mb + 16 * t + cc;
#pragma unroll
      for (int rg = 0; rg < 4; ++rg) {
        float e = __expf(acc[rg]) * zv[rg];
        wacc[t][rg] += (!diag || m <= l0 + rg) ? e : 0.f;
      }
    }
    if (h + 1 < NHEAD) {
      __syncthreads();
      stage(h + 1);
      __syncthreads();
    }
  }
  float* wout = wmean + (long)nb * L_SEQ * L_SEQ;
  _Float16* w16 = wm16 + (long)nb * L_SEQ * L_SEQ;
#pragma unroll
  for (int t = 0; t < 8; ++t) {
    int m = mb + 16 * t + cc;
#pragma unroll
    for (int rg = 0; rg < 4; ++rg) {
      long idx = (long)(l0 + rg) * L_SEQ + m;
      wout[idx] = wacc[t][rg];
      w16[idx] = (_Float16)wacc[t][rg];
    }
  }
}

// ---------------------------------------------------------------------------
extern "C" void kernel_launch(void* const* d_in, const int* in_sizes, int n_in,
                              void* d_out, int out_size, void* d_ws, size_t ws_size,
                              hipStream_t stream)
{
  const float* q  = (const float*)d_in[0];
  const float* k  = (const float*)d_in[1];
  const float* v  = (const float*)d_in[2];
  const float* Wq = (const float*)d_in[3];
  const float* bq = (const float*)d_in[4];
  const float* Wk = (const float*)d_in[5];
  const float* bk = (const float*)d_in[6];
  const float* Wv = (const float*)d_in[7];
  const float* bv = (const float*)d_in[8];
  const float* Wo = (const float*)d_in[9];
  const float* bo = (const float*)d_in[10];

  float* out = (float*)d_out;
  float* wmean = out + (long)L_SEQ * NBATCH * DMODEL;

  if (ws_size < (140UL << 20)) return;

  char* ws = (char*)d_ws;
  _Float16* xh   = (_Float16*)(ws);                   // 48 MB (q,k,v f16)
  _Float16* qph  = (_Float16*)(ws + (48L << 20));     // 16 MB head-major
  _Float16* kph  = (_Float16*)(ws + (64L << 20));     // 16 MB head-major
  _Float16* voT  = (_Float16*)(ws + (80L << 20));     // 16 MB
  _Float16* wm16 = (_Float16*)(ws + (96L << 20));     // 33.6 MB (f16 wmean)
  _Float16* WqT  = (_Float16*)(ws + (130L << 20));    // 2 MB
  _Float16* WkT  = (_Float16*)(ws + (132L << 20));    // 2 MB
  _Float16* WoT  = (_Float16*)(ws + (134L << 20));    // 2 MB
  _Float16* WvoT = (_Float16*)(ws + (136L << 20));    // 2 MB
  float*    bvo  = (float*)   (ws + (138L << 20));    // 4 KB
  float*    Zsum = (float*)   (ws + (138L << 20) + (1L << 16));  // 256 KB

  prep<<<dim3(32, 32, 4), dim3(32, 8, 1), 0, stream>>>(
      Wq, Wk, Wo, WqT, WkT, WoT, bv, bvo, (float4*)Zsum);
  gemm16<true, false><<<dim3(8, 8, 1), 256, 0, stream>>>(
      WoT, 1024, 0, Wv, 1024, 0,
      (float*)nullptr, 0, 0, WvoT, 1024, 0,
      (const float*)nullptr, 0, 1.0f, 1024, 0, 0);
  cvt3<<<dim3(12288, 1, 1), 256, 0, stream>>>(q, k, v, xh);
  projqk<<<dim3(1024, 2, 1), 256, 0, stream>>>(xh, WqT, WkT, bq, bk, qph, kph);
  proj64<<<dim3(256, 1, 4), 256, 0, stream>>>(
      WvoT, 1024, 0, xh + 2 * NQ, 4096, 1024, voT, 2048, 2048L * 1024,
      bvo, 1, 1.0f, 1024, 0, 16);
  s1_kernel<<<dim3(80, NHEAD, NBATCH), 256, 0, stream>>>(qph, kph, Zsum);
  zero_fill<<<dim3(120, 4, 1), 256, 0, stream>>>(wmean);
  s2_kernel<<<dim3(272, NBATCH, 1), 256, 0, stream>>>(qph, kph, Zsum, wmean, wm16);
  out_gemm16<<<dim3(1024, 1, 1), 256, 0, stream>>>(wm16, voT, bo, out);
}

// Round 18
// 296.648 us; speedup vs baseline: 1.0636x; 1.0404x over previous
//
#include <hip/hip_runtime.h>

// R18: s2 XCD-affinity (bijective mc-pair decode: mc∈{xcd,15-xcd}, 34
// blocks/XCD, per-XCD K working set 2MB -> L2-resident); zero_fill folded
// into prep (z=4; strict-upper wmean is never read, only validated).
// Rest = R17 (308.6us best).

#define L_SEQ 2048
#define NBATCH 4
#define DMODEL 1024
#define NHEAD 8
#define SCALING 0.08838834764831845f
#define NQ (2048L * 4 * 1024)

typedef _Float16 f16x8 __attribute__((ext_vector_type(8)));
typedef float f32x4 __attribute__((ext_vector_type(4)));

#define GLOBAL_AS __attribute__((address_space(1)))
#define LDS_AS __attribute__((address_space(3)))

__device__ __forceinline__ unsigned short f2h_bits(float x) {
  _Float16 h = (_Float16)x;
  return __builtin_bit_cast(unsigned short, h);
}

__device__ __forceinline__ void gl_lds16(const void* g, void* l) {
  __builtin_amdgcn_global_load_lds((GLOBAL_AS void*)g, (LDS_AS void*)l, 16, 0, 0);
}

// ---------------------------------------------------------------------------
// prep: z<3 weight transposes; z==3 bias_proj + Zsum zero; z==4 wmean
// strict-upper zero (folded zero_fill — region is write-only for validation).
// ---------------------------------------------------------------------------
__global__ __launch_bounds__(256) void prep(
    const float* __restrict__ Wq, const float* __restrict__ Wk,
    const float* __restrict__ Wo,
    _Float16* __restrict__ WqT, _Float16* __restrict__ WkT,
    _Float16* __restrict__ WoT,
    const float* __restrict__ bv, float* __restrict__ bvo,
    float4* __restrict__ Zsum4, float* __restrict__ wmean)
{
  const int z = (int)blockIdx.z;
  const int tid = threadIdx.y * 32 + threadIdx.x;
  if (z == 4) {                              // wmean strict-upper zeros
    int i = blockIdx.y * 32 + blockIdx.x;
    if (i >= 480) return;
    int t = i % 120, nb = i / 120;
    int by = 0, rem = t;
    while (rem >= 15 - by) { rem -= 15 - by; ++by; }
    const int mc = by + 1 + rem;
    const int tr = tid >> 1, th = tid & 1;
    float4 z4 = {0.f, 0.f, 0.f, 0.f};
    float* p = wmean + (long)nb * L_SEQ * L_SEQ + (long)(by * 128 + tr) * L_SEQ +
               mc * 128 + th * 64;
#pragma unroll
    for (int jj = 0; jj < 16; ++jj) ((float4*)p)[jj] = z4;
    return;
  }
  if (z == 3) {
    if (blockIdx.y == 0 && blockIdx.x < 4) {
      int j = blockIdx.x * 256 + tid;
      float acc = 0.f;
      for (int i = 0; i < DMODEL; ++i) acc += bv[i] * Wo[(long)i * DMODEL + j];
      bvo[j] = acc;
    } else if (blockIdx.y == 1 || blockIdx.y == 2) {
      long idx = ((long)(blockIdx.y - 1) * 32 + blockIdx.x) * 256 + tid;
      if (idx < (long)NBATCH * NHEAD * L_SEQ / 4)
        Zsum4[idx] = (float4){0.f, 0.f, 0.f, 0.f};
    }
    return;
  }
  __shared__ _Float16 tile[32][33];
  const float* in = z == 0 ? Wq : (z == 1 ? Wk : Wo);
  _Float16* outp = z == 0 ? WqT : (z == 1 ? WkT : WoT);
  int r0 = blockIdx.y * 32, c0 = blockIdx.x * 32;
  for (int i = threadIdx.y; i < 32; i += 8)
    tile[i][threadIdx.x] = (_Float16)in[(long)(r0 + i) * 1024 + c0 + threadIdx.x];
  __syncthreads();
  for (int i = threadIdx.y; i < 32; i += 8)
    outp[(long)(c0 + i) * 1024 + r0 + threadIdx.x] = tile[threadIdx.x][i];
}

// ---------------------------------------------------------------------------
__global__ __launch_bounds__(256) void cvt3(
    const float* __restrict__ q, const float* __restrict__ k,
    const float* __restrict__ v, _Float16* __restrict__ xh)
{
  long i = ((long)blockIdx.x * 256 + threadIdx.x) * 8;
  if (i >= 3 * NQ) return;
  int which = (int)(i / NQ);
  const float* src = which == 0 ? q : (which == 1 ? k : v);
  long off = i - (long)which * NQ;
  float4 a = *(const float4*)(src + off);
  float4 b = *(const float4*)(src + off + 4);
  f16x8 h;
  h[0] = (_Float16)a.x; h[1] = (_Float16)a.y; h[2] = (_Float16)a.z; h[3] = (_Float16)a.w;
  h[4] = (_Float16)b.x; h[5] = (_Float16)b.y; h[6] = (_Float16)b.z; h[7] = (_Float16)b.w;
  *(f16x8*)(xh + i) = h;
}

// ---------------------------------------------------------------------------
// gemm16: 128x128 tile. Retained for the small Wvo prep GEMM only.
// ---------------------------------------------------------------------------
template <bool AF16, bool BF16>
__global__ __launch_bounds__(256) void gemm16(
    const void* __restrict__ Ap, long lda, long a_bs,
    const void* __restrict__ Bp, long ldb, long b_bs,
    float* __restrict__ C, long ldc, long c_bs,
    _Float16* __restrict__ Ch, long ldch, long ch_bs,
    const float* __restrict__ bias, int bias_row, float alpha, int K,
    int causal, int cmode)
{
  __shared__ __align__(16) _Float16 As[128][64];
  __shared__ __align__(16) _Float16 Bs[128][64];
  const int tid = threadIdx.x;
  const int lane = tid & 63, wv = tid >> 6;
  const int g = lane >> 4, cc = lane & 15;
  const int wm = wv >> 1, wn = wv & 1;
  const long m0 = (long)blockIdx.y * 128;
  const long n0 = (long)blockIdx.x * 128;

  const float* Af = nullptr; const _Float16* Ah = nullptr;
  const float* Bf = nullptr; const _Float16* Bh = nullptr;
  if constexpr (AF16) Ah = (const _Float16*)Ap + (long)blockIdx.z * a_bs;
  else                Af = (const float*)Ap + (long)blockIdx.z * a_bs;
  if constexpr (BF16) Bh = (const _Float16*)Bp + (long)blockIdx.z * b_bs;
  else                Bf = (const float*)Bp + (long)blockIdx.z * b_bs;

  int Keff = K;
  if (causal) { int lim = (int)m0 + 128; if (lim < K) Keff = lim; }
  const int NT = Keff >> 6;

  f32x4 acc[4][4] = {};
  char* AsB = (char*)&As[0][0];
  char* BsB = (char*)&Bs[0][0];

  for (int kt = 0; kt < NT; ++kt) {
    const long k0 = (long)kt << 6;
    __syncthreads();
    if constexpr (AF16) {
#pragma unroll
      for (int i = 0; i < 4; ++i) {
        int r = 32 * wv + 8 * i + (lane >> 3);
        int gc = (lane & 7) ^ (r & 7);
        gl_lds16(Ah + (m0 + r) * lda + k0 + gc * 8, &As[32 * wv + 8 * i][0]);
      }
    } else {
#pragma unroll
      for (int p = 0; p < 8; ++p) {
        int r = p * 16 + (tid >> 4);
        float4 vv = *(const float4*)(Af + (m0 + r) * lda + k0 + (tid & 15) * 4);
        ushort4 hh;
        hh.x = f2h_bits(vv.x); hh.y = f2h_bits(vv.y);
        hh.z = f2h_bits(vv.z); hh.w = f2h_bits(vv.w);
        *(ushort4*)(AsB + r * 128 + (((tid & 15) * 8) ^ ((r & 7) << 4))) = hh;
      }
    }
    if constexpr (BF16) {
#pragma unroll
      for (int i = 0; i < 4; ++i) {
        int r = 32 * wv + 8 * i + (lane >> 3);
        int gc = (lane & 7) ^ (r & 7);
        gl_lds16(Bh + (n0 + r) * ldb + k0 + gc * 8, &Bs[32 * wv + 8 * i][0]);
      }
    } else {
#pragma unroll
      for (int p = 0; p < 8; ++p) {
        int r = p * 16 + (tid >> 4);
        float4 vv = *(const float4*)(Bf + (n0 + r) * ldb + k0 + (tid & 15) * 4);
        ushort4 hh;
        hh.x = f2h_bits(vv.x); hh.y = f2h_bits(vv.y);
        hh.z = f2h_bits(vv.z); hh.w = f2h_bits(vv.w);
        *(ushort4*)(BsB + r * 128 + (((tid & 15) * 8) ^ ((r & 7) << 4))) = hh;
      }
    }
    __syncthreads();
#pragma unroll
    for (int s = 0; s < 2; ++s) {
      f16x8 af[4], bfr[4];
#pragma unroll
      for (int mi = 0; mi < 4; ++mi) {
        int r = wm * 64 + mi * 16 + cc;
        af[mi] = *(const f16x8*)(AsB + r * 128 + ((s * 64 + 16 * g) ^ ((r & 7) << 4)));
      }
#pragma unroll
      for (int ni = 0; ni < 4; ++ni) {
        int r = wn * 64 + ni * 16 + cc;
        bfr[ni] = *(const f16x8*)(BsB + r * 128 + ((s * 64 + 16 * g) ^ ((r & 7) << 4)));
      }
#pragma unroll
      for (int mi = 0; mi < 4; ++mi)
#pragma unroll
        for (int ni = 0; ni < 4; ++ni)
          acc[mi][ni] = __builtin_amdgcn_mfma_f32_16x16x32_f16(af[mi], bfr[ni], acc[mi][ni], 0, 0, 0);
    }
  }

  float* Cp = C ? C + (long)blockIdx.z * c_bs : nullptr;
  _Float16* Chp = Ch ? Ch + (long)blockIdx.z * ch_bs : nullptr;
#pragma unroll
  for (int ni = 0; ni < 4; ++ni) {
    long col = n0 + wn * 64 + ni * 16 + cc;
    float bcol = (bias && !bias_row) ? bias[col] : 0.0f;
#pragma unroll
    for (int mi = 0; mi < 4; ++mi) {
      long row0 = m0 + wm * 64 + mi * 16 + 4 * g;
#pragma unroll
      for (int rg = 0; rg < 4; ++rg) {
        long row = row0 + rg;
        float b = (bias && bias_row) ? bias[row] : bcol;
        float vv = (acc[mi][ni][rg] + b) * alpha;
        if (Cp) Cp[row * ldc + col] = vv;
        if (Chp) {
          if (cmode == 1) {
            long idx = (((row & 3) * NHEAD + (col >> 7)) * (long)L_SEQ + (row >> 2)) * 128 +
                       (col & 127);
            Chp[idx] = (_Float16)vv;
          } else {
            Chp[row * ldch + col] = (_Float16)vv;
          }
        }
      }
    }
  }
}

// ---------------------------------------------------------------------------
// projqk (R17: BK=64 + XCD-affinity).
// ---------------------------------------------------------------------------
__global__ __launch_bounds__(256) void projqk(
    const _Float16* __restrict__ xh, const _Float16* __restrict__ WqT,
    const _Float16* __restrict__ WkT, const float* __restrict__ bq,
    const float* __restrict__ bk, _Float16* __restrict__ qph,
    _Float16* __restrict__ kph)
{
  __shared__ __align__(16) _Float16 As[64][64];
  __shared__ __align__(16) _Float16 Bs[128][64];
  const int tid = threadIdx.x, lane = tid & 63, wv = tid >> 6;
  const int g = lane >> 4, cc = lane & 15;
  const int wm = wv >> 1, wn = wv & 1;
  const int sel = (int)blockIdx.y;
  const _Float16* A = xh + (long)sel * NQ;
  const _Float16* B = sel ? WkT : WqT;
  const float* bias = sel ? bk : bq;
  const float alpha = sel ? 1.0f : SCALING;
  _Float16* dst = sel ? kph : qph;
  const int bid = (int)blockIdx.x;
  const int j = bid >> 3;
  const int mt = (bid & 7) * 16 + (j & 15);   // A-tile pinned to XCD bid&7
  const int nt = j >> 4;
  const long m0 = (long)mt * 64;
  const long n0 = (long)nt * 128;

  f32x4 acc[2][4] = {};
  char* AsB = (char*)&As[0][0];
  char* BsB = (char*)&Bs[0][0];

  for (int kt = 0; kt < 16; ++kt) {
    const long k0 = (long)kt << 6;
    __syncthreads();
#pragma unroll
    for (int i = 0; i < 2; ++i) {
      int r = 16 * wv + 8 * i + (lane >> 3);
      int gc = (lane & 7) ^ (r & 7);
      gl_lds16(A + (m0 + r) * 1024 + k0 + gc * 8, &As[16 * wv + 8 * i][0]);
    }
#pragma unroll
    for (int i = 0; i < 4; ++i) {
      int r = 32 * wv + 8 * i + (lane >> 3);
      int gc = (lane & 7) ^ (r & 7);
      gl_lds16(B + (n0 + r) * 1024 + k0 + gc * 8, &Bs[32 * wv + 8 * i][0]);
    }
    __syncthreads();
#pragma unroll
    for (int s = 0; s < 2; ++s) {
      f16x8 af[2], bfr[4];
#pragma unroll
      for (int mi = 0; mi < 2; ++mi) {
        int r = wm * 32 + mi * 16 + cc;
        af[mi] = *(const f16x8*)(AsB + r * 128 + ((s * 64 + 16 * g) ^ ((r & 7) << 4)));
      }
#pragma unroll
      for (int ni = 0; ni < 4; ++ni) {
        int r = wn * 64 + ni * 16 + cc;
        bfr[ni] = *(const f16x8*)(BsB + r * 128 + ((s * 64 + 16 * g) ^ ((r & 7) << 4)));
      }
#pragma unroll
      for (int mi = 0; mi < 2; ++mi)
#pragma unroll
        for (int ni = 0; ni < 4; ++ni)
          acc[mi][ni] = __builtin_amdgcn_mfma_f32_16x16x32_f16(af[mi], bfr[ni], acc[mi][ni], 0, 0, 0);
    }
  }

#pragma unroll
  for (int ni = 0; ni < 4; ++ni) {
    long col = n0 + wn * 64 + ni * 16 + cc;
    float bcol = bias[col];
#pragma unroll
    for (int mi = 0; mi < 2; ++mi) {
      long row0 = m0 + wm * 32 + mi * 16 + 4 * g;
#pragma unroll
      for (int rg = 0; rg < 4; ++rg) {
        long row = row0 + rg;
        float vv = (acc[mi][ni][rg] + bcol) * alpha;
        long idx = (((row & 3) * NHEAD + (col >> 7)) * (long)L_SEQ + (row >> 2)) * 128 +
                   (col & 127);
        dst[idx] = (_Float16)vv;
      }
    }
  }
}

// ---------------------------------------------------------------------------
// proj64 (R8, proven): 64x128 tile, BK=64 dual gl_lds staging. For voT.
// ---------------------------------------------------------------------------
__global__ __launch_bounds__(256) void proj64(
    const _Float16* __restrict__ Ap, long lda, long a_bs,
    const _Float16* __restrict__ Bp, long ldb, long b_bs,
    _Float16* __restrict__ Ch, long ldch, long ch_bs,
    const float* __restrict__ bias, int bias_row, float alpha, int K,
    int cmode, int ntiles)
{
  __shared__ __align__(16) _Float16 As[64][64];
  __shared__ __align__(16) _Float16 Bs[128][64];
  const int tid = threadIdx.x, lane = tid & 63, wv = tid >> 6;
  const int g = lane >> 4, cc = lane & 15;
  const int wm = wv >> 1, wn = wv & 1;
  const int fi = (int)blockIdx.x;
  const int by = fi / ntiles, nc = fi % ntiles;
  const long m0 = (long)by * 64;
  const long n0 = (long)nc * 128;
  const _Float16* A = Ap + (long)blockIdx.z * a_bs;
  const _Float16* B = Bp + (long)blockIdx.z * b_bs;
  const int NT = K >> 6;

  f32x4 acc[2][4] = {};
  char* AsB = (char*)&As[0][0];
  char* BsB = (char*)&Bs[0][0];

  for (int kt = 0; kt < NT; ++kt) {
    const long k0 = (long)kt << 6;
    __syncthreads();
#pragma unroll
    for (int i = 0; i < 2; ++i) {
      int r = 16 * wv + 8 * i + (lane >> 3);
      int gc = (lane & 7) ^ (r & 7);
      gl_lds16(A + (m0 + r) * lda + k0 + gc * 8, &As[16 * wv + 8 * i][0]);
    }
#pragma unroll
    for (int i = 0; i < 4; ++i) {
      int r = 32 * wv + 8 * i + (lane >> 3);
      int gc = (lane & 7) ^ (r & 7);
      gl_lds16(B + (n0 + r) * ldb + k0 + gc * 8, &Bs[32 * wv + 8 * i][0]);
    }
    __syncthreads();
#pragma unroll
    for (int s = 0; s < 2; ++s) {
      f16x8 af[2], bfr[4];
#pragma unroll
      for (int mi = 0; mi < 2; ++mi) {
        int r = wm * 32 + mi * 16 + cc;
        af[mi] = *(const f16x8*)(AsB + r * 128 + ((s * 64 + 16 * g) ^ ((r & 7) << 4)));
      }
#pragma unroll
      for (int ni = 0; ni < 4; ++ni) {
        int r = wn * 64 + ni * 16 + cc;
        bfr[ni] = *(const f16x8*)(BsB + r * 128 + ((s * 64 + 16 * g) ^ ((r & 7) << 4)));
      }
#pragma unroll
      for (int mi = 0; mi < 2; ++mi)
#pragma unroll
        for (int ni = 0; ni < 4; ++ni)
          acc[mi][ni] = __builtin_amdgcn_mfma_f32_16x16x32_f16(af[mi], bfr[ni], acc[mi][ni], 0, 0, 0);
    }
  }

  _Float16* Chp = Ch + (long)blockIdx.z * ch_bs;
#pragma unroll
  for (int ni = 0; ni < 4; ++ni) {
    long col = n0 + wn * 64 + ni * 16 + cc;
    float bcol = bias_row ? 0.0f : bias[col];
#pragma unroll
    for (int mi = 0; mi < 2; ++mi) {
      long row0 = m0 + wm * 32 + mi * 16 + 4 * g;
#pragma unroll
      for (int rg = 0; rg < 4; ++rg) {
        long row = row0 + rg;
        float b = bias_row ? bias[row] : bcol;
        float vv = (acc[mi][ni][rg] + b) * alpha;
        if (cmode == 1) {
          long idx = (((row & 3) * NHEAD + (col >> 7)) * (long)L_SEQ + (row >> 2)) * 128 +
                     (col & 127);
          Chp[idx] = (_Float16)vv;
        } else {
          Chp[row * ldch + col] = (_Float16)vv;
        }
      }
    }
  }
}

// ---------------------------------------------------------------------------
// out_gemm16 (R17: BK=128 + XCD-affinity).
// ---------------------------------------------------------------------------
__global__ __launch_bounds__(256) void out_gemm16(
    const _Float16* __restrict__ wm16, const _Float16* __restrict__ voT,
    const float* __restrict__ bo, float* __restrict__ out)
{
  __shared__ __align__(16) _Float16 As[64][128];   // 16 KB
  __shared__ __align__(16) _Float16 Bs[128][128];  // 32 KB
  const int tid = threadIdx.x, lane = tid & 63, wv = tid >> 6;
  const int g = lane >> 4, cc = lane & 15;
  const int wm = wv >> 1, wn = wv & 1;
  const int bid = (int)blockIdx.x;
  const int j = bid >> 3;
  const int p = (j >> 3) * 8 + (bid & 7);   // (by,nb) group pinned to XCD
  const int by = 31 - (p >> 2);             // heavy (long-K) groups first
  const int nb = p & 3;
  const int nc = j & 7;
  const long m0 = (long)by * 64;
  const long n0 = (long)nc * 128;
  const _Float16* A = wm16 + (long)nb * L_SEQ * L_SEQ;
  const _Float16* B = voT + (long)nb * 2048L * 1024;
  const int NT = (by + 2) >> 1;
  const int srow = lane >> 4, scl = lane & 15;

  f32x4 acc[2][4] = {};
  char* AsB = (char*)&As[0][0];
  char* BsB = (char*)&Bs[0][0];

  for (int kt = 0; kt < NT; ++kt) {
    const long k0 = (long)kt << 7;
    __syncthreads();
#pragma unroll
    for (int i = 0; i < 4; ++i) {
      int r = 16 * wv + 4 * i + srow;
      int gc = scl ^ (r & 7);
      gl_lds16(A + (m0 + r) * 2048 + k0 + gc * 8, &As[16 * wv + 4 * i][0]);
    }
#pragma unroll
    for (int i = 0; i < 8; ++i) {
      int r = 32 * wv + 4 * i + srow;
      int gc = scl ^ (r & 7);
      gl_lds16(B + (n0 + r) * 2048 + k0 + gc * 8, &Bs[32 * wv + 4 * i][0]);
    }
    __syncthreads();
#pragma unroll
    for (int s = 0; s < 4; ++s) {
      f16x8 af[2], bfr[4];
#pragma unroll
      for (int mi = 0; mi < 2; ++mi) {
        int r = wm * 32 + mi * 16 + cc;
        af[mi] = *(const f16x8*)(AsB + r * 256 + (((4 * s + g) ^ (r & 7)) << 4));
      }
#pragma unroll
      for (int ni = 0; ni < 4; ++ni) {
        int r = wn * 64 + ni * 16 + cc;
        bfr[ni] = *(const f16x8*)(BsB + r * 256 + (((4 * s + g) ^ (r & 7)) << 4));
      }
#pragma unroll
      for (int mi = 0; mi < 2; ++mi)
#pragma unroll
        for (int ni = 0; ni < 4; ++ni)
          acc[mi][ni] = __builtin_amdgcn_mfma_f32_16x16x32_f16(af[mi], bfr[ni], acc[mi][ni], 0, 0, 0);
    }
  }

#pragma unroll
  for (int ni = 0; ni < 4; ++ni) {
    long col = n0 + wn * 64 + ni * 16 + cc;
    float b = bo[col];
#pragma unroll
    for (int mi = 0; mi < 2; ++mi) {
      long l0 = m0 + wm * 32 + mi * 16 + 4 * g;
#pragma unroll
      for (int rg = 0; rg < 4; ++rg)
        out[(l0 + rg) * 4096 + nb * 1024 + col] = acc[mi][ni][rg] + b;
    }
  }
}

// ---------------------------------------------------------------------------
// S1 (R10, proven): K-split partial Zsum via atomicAdd. 80-segment grid.
// ---------------------------------------------------------------------------
__global__ __launch_bounds__(256) void s1_kernel(
    const _Float16* __restrict__ qph, const _Float16* __restrict__ kph,
    float* __restrict__ Zsum)
{
  __shared__ __align__(16) _Float16 Qs[64][128];
  __shared__ __align__(16) _Float16 Ks[64][128];
  const int tid = threadIdx.x, lane = tid & 63, w = tid >> 6;
  const int g = lane >> 4, cc = lane & 15;
  const int h = blockIdx.y, nb = blockIdx.z;
  int fi = 79 - (int)blockIdx.x;
  int by, seg;
  if (fi < 8)       { by = fi;                  seg = 0; }
  else if (fi < 24) { int t = fi - 8;  by = 8  + (t >> 1); seg = t & 1; }
  else if (fi < 48) { int t = fi - 24; by = 16 + t / 3;    seg = t % 3; }
  else              { int t = fi - 48; by = 24 + (t >> 2); seg = t & 3; }
  const int lb = by * 64;
  const int c0 = seg * 8;
  const int cEnd = min(c0 + 8, by + 1);
  const int srow = lane >> 4, scl = lane & 15;
  const long hb = ((long)(nb * NHEAD + h)) * L_SEQ * 128;
  char* QsB = (char*)&Qs[0][0];
  char* KsB = (char*)&Ks[0][0];

#pragma unroll
  for (int i = 0; i < 4; ++i) {
    int r = 16 * w + 4 * i + srow;
    int gc = scl ^ (r & 7);
    gl_lds16(&qph[hb + (long)(lb + r) * 128 + gc * 8], &Qs[16 * w + 4 * i][0]);
  }
  auto stageK = [&](int ch) {
#pragma unroll
    for (int i = 0; i < 4; ++i) {
      int r = 16 * w + 4 * i + srow;
      int gc = scl ^ (r & 7);
      gl_lds16(&kph[hb + (long)(ch * 64 + r) * 128 + gc * 8], &Ks[16 * w + 4 * i][0]);
    }
  };
  stageK(c0);
  __syncthreads();

  f16x8 qf[4];
  {
    int r = 16 * w + cc;
#pragma unroll
    for (int s = 0; s < 4; ++s)
      qf[s] = *(const f16x8*)(QsB + r * 256 + ((64 * s + 16 * g) ^ ((r & 7) << 4)));
  }

  f32x4 zacc = {0.f, 0.f, 0.f, 0.f};
  const int l0 = lb + 16 * w + 4 * g;
  for (int ch = c0; ch < cEnd; ++ch) {
#pragma unroll
    for (int t = 0; t < 4; ++t) {
      int kr = 16 * t + cc;
      f32x4 acc = {0.f, 0.f, 0.f, 0.f};
#pragma unroll
      for (int s = 0; s < 4; ++s) {
        f16x8 kf = *(const f16x8*)(KsB + kr * 256 + ((64 * s + 16 * g) ^ ((kr & 7) << 4)));
        acc = __builtin_amdgcn_mfma_f32_16x16x32_f16(qf[s], kf, acc, 0, 0, 0);
      }
      int m = ch * 64 + 16 * t + cc;
#pragma unroll
      for (int rg = 0; rg < 4; ++rg) {
        float e = __expf(acc[rg]);
        zacc[rg] += (m <= l0 + rg) ? e : 0.f;
      }
    }
    if (ch + 1 < cEnd) {
      __syncthreads();
      stageK(ch + 1);
      __syncthreads();
    }
  }
#pragma unroll
  for (int rg = 0; rg < 4; ++rg) {
    float vv = zacc[rg];
    vv += __shfl_xor(vv, 1, 16);
    vv += __shfl_xor(vv, 2, 16);
    vv += __shfl_xor(vv, 4, 16);
    vv += __shfl_xor(vv, 8, 16);
    if (cc == 0)
      atomicAdd(&Zsum[((long)nb * NHEAD + h) * L_SEQ + l0 + rg], vv);
  }
}

// ---------------------------------------------------------------------------
// S2 (R14 tile + XCD-affinity): mc pinned per XCD via pair decode
// (xcd, 15-xcd): counts (32-2mc) sum to 34 = blocks/XCD. Heavy-by first
// within each XCD. Per-XCD K working set = 2 panels x 4nb x 256KB = 2MB.
// ---------------------------------------------------------------------------
__global__ __launch_bounds__(256) void s2_kernel(
    const _Float16* __restrict__ qph, const _Float16* __restrict__ kph,
    const float* __restrict__ Zsum, float* __restrict__ wmean,
    _Float16* __restrict__ wm16)
{
  __shared__ __align__(16) _Float16 Qs[64][128];
  __shared__ __align__(16) _Float16 Ks[128][128];
  __shared__ float zl[NHEAD][64];
  const int tid = threadIdx.x, lane = tid & 63, w = tid >> 6;
  const int g = lane >> 4, cc = lane & 15;
  const int nb = blockIdx.y;
  const int x = (int)blockIdx.x;
  const int xcd = x & 7, idx = x >> 3;
  const int cnt0 = 32 - 2 * xcd;            // blocks with mc = xcd
  int mc, by;
  if (idx < cnt0) { mc = xcd;      by = 31 - idx; }
  else            { mc = 15 - xcd; by = 31 - (idx - cnt0); }
  const int lb = by * 64, mb = mc * 128;
  const bool diag = (mb + 127 > lb);
  const int srow = lane >> 4, scl = lane & 15;
  char* QsB = (char*)&Qs[0][0];
  char* KsB = (char*)&Ks[0][0];

  for (int i = tid; i < NHEAD * 64; i += 256)
    zl[i >> 6][i & 63] =
        1.0f / (8.0f * Zsum[((long)nb * NHEAD + (i >> 6)) * L_SEQ + lb + (i & 63)]);

  auto stage = [&](int h) {
    const long qb = ((long)(nb * NHEAD + h) * L_SEQ + lb) * 128;
    const long kb = ((long)(nb * NHEAD + h) * L_SEQ + mb) * 128;
#pragma unroll
    for (int i = 0; i < 4; ++i) {
      int r = 16 * w + 4 * i + srow;
      int gc = scl ^ (r & 7);
      gl_lds16(&qph[qb + (long)r * 128 + gc * 8], &Qs[16 * w + 4 * i][0]);
    }
#pragma unroll
    for (int i = 0; i < 8; ++i) {
      int r = 32 * w + 4 * i + srow;
      int gc = scl ^ (r & 7);
      gl_lds16(&kph[kb + (long)r * 128 + gc * 8], &Ks[32 * w + 4 * i][0]);
    }
  };
  stage(0);
  __syncthreads();

  f32x4 wacc[8] = {};
  const int l0 = lb + 16 * w + 4 * g;
  for (int h = 0; h < NHEAD; ++h) {
    f16x8 qf[4];
    int qr = 16 * w + cc;
#pragma unroll
    for (int s = 0; s < 4; ++s)
      qf[s] = *(const f16x8*)(QsB + qr * 256 + ((64 * s + 16 * g) ^ ((qr & 7) << 4)));
    f32x4 zv = *(const f32x4*)&zl[h][16 * w + 4 * g];
#pragma unroll
    for (int t = 0; t < 8; ++t) {
      int kr = 16 * t + cc;
      f32x4 acc = {0.f, 0.f, 0.f, 0.f};
#pragma unroll
      for (int s = 0; s < 4; ++s) {
        f16x8 kf = *(const f16x8*)(KsB + kr * 256 + ((64 * s + 16 * g) ^ ((kr & 7) << 4)));
        acc = __builtin_amdgcn_mfma_f32_16x16x32_f16(qf[s], kf, acc, 0, 0, 0);
      }
      int m = mb + 16 * t + cc;
#pragma unroll
      for (int rg = 0; rg < 4; ++rg) {
        float e = __expf(acc[rg]) * zv[rg];
        wacc[t][rg] += (!diag || m <= l0 + rg) ? e : 0.f;
      }
    }
    if (h + 1 < NHEAD) {
      __syncthreads();
      stage(h + 1);
      __syncthreads();
    }
  }
  float* wout = wmean + (long)nb * L_SEQ * L_SEQ;
  _Float16* w16 = wm16 + (long)nb * L_SEQ * L_SEQ;
#pragma unroll
  for (int t = 0; t < 8; ++t) {
    int m = mb + 16 * t + cc;
#pragma unroll
    for (int rg = 0; rg < 4; ++rg) {
      long idx2 = (long)(l0 + rg) * L_SEQ + m;
      wout[idx2] = wacc[t][rg];
      w16[idx2] = (_Float16)wacc[t][rg];
    }
  }
}

// ---------------------------------------------------------------------------
extern "C" void kernel_launch(void* const* d_in, const int* in_sizes, int n_in,
                              void* d_out, int out_size, void* d_ws, size_t ws_size,
                              hipStream_t stream)
{
  const float* q  = (const float*)d_in[0];
  const float* k  = (const float*)d_in[1];
  const float* v  = (const float*)d_in[2];
  const float* Wq = (const float*)d_in[3];
  const float* bq = (const float*)d_in[4];
  const float* Wk = (const float*)d_in[5];
  const float* bk = (const float*)d_in[6];
  const float* Wv = (const float*)d_in[7];
  const float* bv = (const float*)d_in[8];
  const float* Wo = (const float*)d_in[9];
  const float* bo = (const float*)d_in[10];

  float* out = (float*)d_out;
  float* wmean = out + (long)L_SEQ * NBATCH * DMODEL;

  if (ws_size < (140UL << 20)) return;

  char* ws = (char*)d_ws;
  _Float16* xh   = (_Float16*)(ws);                   // 48 MB (q,k,v f16)
  _Float16* qph  = (_Float16*)(ws + (48L << 20));     // 16 MB head-major
  _Float16* kph  = (_Float16*)(ws + (64L << 20));     // 16 MB head-major
  _Float16* voT  = (_Float16*)(ws + (80L << 20));     // 16 MB
  _Float16* wm16 = (_Float16*)(ws + (96L << 20));     // 33.6 MB (f16 wmean)
  _Float16* WqT  = (_Float16*)(ws + (130L << 20));    // 2 MB
  _Float16* WkT  = (_Float16*)(ws + (132L << 20));    // 2 MB
  _Float16* WoT  = (_Float16*)(ws + (134L << 20));    // 2 MB
  _Float16* WvoT = (_Float16*)(ws + (136L << 20));    // 2 MB
  float*    bvo  = (float*)   (ws + (138L << 20));    // 4 KB
  float*    Zsum = (float*)   (ws + (138L << 20) + (1L << 16));  // 256 KB

  prep<<<dim3(32, 32, 5), dim3(32, 8, 1), 0, stream>>>(
      Wq, Wk, Wo, WqT, WkT, WoT, bv, bvo, (float4*)Zsum, wmean);
  gemm16<true, false><<<dim3(8, 8, 1), 256, 0, stream>>>(
      WoT, 1024, 0, Wv, 1024, 0,
      (float*)nullptr, 0, 0, WvoT, 1024, 0,
      (const float*)nullptr, 0, 1.0f, 1024, 0, 0);
  cvt3<<<dim3(12288, 1, 1), 256, 0, stream>>>(q, k, v, xh);
  projqk<<<dim3(1024, 2, 1), 256, 0, stream>>>(xh, WqT, WkT, bq, bk, qph, kph);
  proj64<<<dim3(256, 1, 4), 256, 0, stream>>>(
      WvoT, 1024, 0, xh + 2 * NQ, 4096, 1024, voT, 2048, 2048L * 1024,
      bvo, 1, 1.0f, 1024, 0, 16);
  s1_kernel<<<dim3(80, NHEAD, NBATCH), 256, 0, stream>>>(qph, kph, Zsum);
  s2_kernel<<<dim3(272, NBATCH, 1), 256, 0, stream>>>(qph, kph, Zsum, wmean, wm16);
  out_gemm16<<<dim3(1024, 1, 1), 256, 0, stream>>>(wm16, voT, bo, out);
}